// Round 6
// baseline (461.436 us; speedup 1.0000x reference)
//
#include <hip/hip_runtime.h>

// EBT transformer block on MI355X. All GEMMs via mfma_f32_16x16x32_bf16
// (fp32 accumulate) with global_load_lds staging (m97 structure);
// flash attention with KV-split=4 (occupancy), swapped QK^T, permlane
// softmax + P re-layout, bf16 partials + combine pass.

typedef __attribute__((ext_vector_type(8))) __bf16 bf16x8;
typedef __attribute__((ext_vector_type(8))) short short8;
typedef __attribute__((ext_vector_type(4))) short short4v;
typedef __attribute__((ext_vector_type(4))) float f32x4;
typedef __attribute__((ext_vector_type(4))) float float4v;
typedef __attribute__((ext_vector_type(4))) unsigned int u32x4;

#define CDIM   768
#define HEADS  12
#define DH     64
#define SEQ    2048
#define BATCH  2
#define MROWS  4096      // B*S
#define QKV_N  2304      // 3*H*D
#define INTER  2048
#define GU_N   4096      // 2*INTER
#define NSPLIT 4
#define KCHUNK (SEQ / NSPLIT)   // 512
#define BH     (BATCH * HEADS)  // 24

// log2(e)/8 folded into Q so scores are already in exp2 domain.
#define QSCALE 0.18033688011112043f

static __device__ __forceinline__ unsigned short f2bf(float f) {
  unsigned int u = __builtin_bit_cast(unsigned int, f);
  u += 0x7fffu + ((u >> 16) & 1u);
  return (unsigned short)(u >> 16);
}
static __device__ __forceinline__ float bf2f(unsigned short u) {
  return __builtin_bit_cast(float, ((unsigned int)u) << 16);
}

static __device__ __forceinline__ bf16x8 ld8(const unsigned short* p) {
  return __builtin_bit_cast(bf16x8, *reinterpret_cast<const short8*>(p));
}

static __device__ __forceinline__ unsigned pack2bf(float lo, float hi) {
  unsigned short a = __builtin_bit_cast(unsigned short, (__bf16)lo);
  unsigned short b = __builtin_bit_cast(unsigned short, (__bf16)hi);
  return (unsigned)a | ((unsigned)b << 16);
}

// register-transpose building block: exchange reg-pair bit with lane bit5/bit4
static __device__ __forceinline__ void pl32swap(unsigned& a, unsigned& b) {
  auto r = __builtin_amdgcn_permlane32_swap(a, b, false, false);
  a = r[0]; b = r[1];
}
static __device__ __forceinline__ void pl16swap(unsigned& a, unsigned& b) {
  auto r = __builtin_amdgcn_permlane16_swap(a, b, false, false);
  a = r[0]; b = r[1];
}
// butterfly reduce across lane bit5 / bit4: one permlane + one op
static __device__ __forceinline__ float red32max(float x) {
  unsigned xi = __builtin_bit_cast(unsigned, x);
  auto r = __builtin_amdgcn_permlane32_swap(xi, xi, false, false);
  return fmaxf(__builtin_bit_cast(float, r[0]), __builtin_bit_cast(float, r[1]));
}
static __device__ __forceinline__ float red16max(float x) {
  unsigned xi = __builtin_bit_cast(unsigned, x);
  auto r = __builtin_amdgcn_permlane16_swap(xi, xi, false, false);
  return fmaxf(__builtin_bit_cast(float, r[0]), __builtin_bit_cast(float, r[1]));
}
static __device__ __forceinline__ float red32sum(float x) {
  unsigned xi = __builtin_bit_cast(unsigned, x);
  auto r = __builtin_amdgcn_permlane32_swap(xi, xi, false, false);
  return __builtin_bit_cast(float, r[0]) + __builtin_bit_cast(float, r[1]);
}
static __device__ __forceinline__ float red16sum(float x) {
  unsigned xi = __builtin_bit_cast(unsigned, x);
  auto r = __builtin_amdgcn_permlane16_swap(xi, xi, false, false);
  return __builtin_bit_cast(float, r[0]) + __builtin_bit_cast(float, r[1]);
}

// ---------------------------------------------------------------- casts ----
__global__ __launch_bounds__(256) void cast_all(
    const float* __restrict__ h, const float* __restrict__ wqkv,
    const float* __restrict__ wo, const float* __restrict__ wgu,
    const float* __restrict__ wd,
    unsigned short* __restrict__ hb, unsigned short* __restrict__ wqkvb,
    unsigned short* __restrict__ wob, unsigned short* __restrict__ wgub,
    unsigned short* __restrict__ wdb) {
  const int n0 = 786432, n1 = 442368, n2 = 147456, n3 = 786432, n4 = 393216;
  const int total = n0 + n1 + n2 + n3 + n4;   // in float4 units
  for (int i = blockIdx.x * blockDim.x + threadIdx.x; i < total;
       i += gridDim.x * blockDim.x) {
    int j = i;
    const float* src; unsigned short* dst;
    if      (j < n0)            { src = h;    dst = hb;    }
    else if ((j -= n0) < n1)    { src = wqkv; dst = wqkvb; }
    else if ((j -= n1) < n2)    { src = wo;   dst = wob;   }
    else if ((j -= n2) < n3)    { src = wgu;  dst = wgub;  }
    else    { j -= n3;            src = wd;   dst = wdb;   }
    float4v v = *reinterpret_cast<const float4v*>(src + 4 * (size_t)j);
    short4v o;
#pragma unroll
    for (int e = 0; e < 4; ++e) o[e] = (short)f2bf(v[e]);
    *reinterpret_cast<short4v*>(dst + 4 * (size_t)j) = o;
  }
}

// ----------------------------------------------------------------- GEMM ----
// C[m][n] = sum_k A[m][k] * W[n][k].  128x128 block tile, BK=32, 4 waves,
// global_load_lds staging (m97 structure). Mm,Nn %128==0, Kk %32==0.
template <bool BF16OUT>
__global__ __launch_bounds__(256) void gemm_lds(
    const unsigned short* __restrict__ A, const unsigned short* __restrict__ W,
    void* __restrict__ Cout, int Mm, int Nn, int Kk) {
  __shared__ unsigned short Alds[4096];   // [128][32]
  __shared__ unsigned short Blds[4096];   // [128][32]
  const int t = threadIdx.x;
  const int lane = t & 63, w = t >> 6;
  const int lr = lane & 15, lg = lane >> 4;
  const int row0 = blockIdx.y * 128, col0 = blockIdx.x * 128;
  const int wr = w >> 1, wc = w & 1;

  const unsigned short* ga = A + (size_t)(row0 + (t >> 2)) * Kk + (t & 3) * 8;
  const unsigned short* gb = W + (size_t)(col0 + (t >> 2)) * Kk + (t & 3) * 8;
  const size_t g64 = (size_t)64 * Kk;
  unsigned short* la0 = Alds + w * 512;   // wave-uniform LDS base
  unsigned short* lb0 = Blds + w * 512;
  const unsigned short* ra = Alds + (wr * 64 + lr) * 32 + lg * 8;
  const unsigned short* rb = Blds + (wc * 64 + lr) * 32 + lg * 8;

  f32x4 acc[4][4] = {};
  for (int k0 = 0; k0 < Kk; k0 += 32) {
    __builtin_amdgcn_global_load_lds((const unsigned int*)(ga + k0),
                                     (unsigned int*)la0, 16, 0, 0);
    __builtin_amdgcn_global_load_lds((const unsigned int*)(ga + k0 + g64),
                                     (unsigned int*)(la0 + 2048), 16, 0, 0);
    __builtin_amdgcn_global_load_lds((const unsigned int*)(gb + k0),
                                     (unsigned int*)lb0, 16, 0, 0);
    __builtin_amdgcn_global_load_lds((const unsigned int*)(gb + k0 + g64),
                                     (unsigned int*)(lb0 + 2048), 16, 0, 0);
    __syncthreads();
    bf16x8 af[4], bfr[4];
#pragma unroll
    for (int m = 0; m < 4; ++m) af[m] = ld8(ra + m * 512);
#pragma unroll
    for (int n = 0; n < 4; ++n) bfr[n] = ld8(rb + n * 512);
    __builtin_amdgcn_s_setprio(1);
#pragma unroll
    for (int m = 0; m < 4; ++m)
#pragma unroll
      for (int n = 0; n < 4; ++n)
        acc[m][n] = __builtin_amdgcn_mfma_f32_16x16x32_bf16(af[m], bfr[n],
                                                            acc[m][n], 0, 0, 0);
    __builtin_amdgcn_s_setprio(0);
    __syncthreads();
  }
#pragma unroll
  for (int m = 0; m < 4; ++m)
#pragma unroll
    for (int j = 0; j < 4; ++j) {
      const size_t roff = (size_t)(row0 + wr * 64 + m * 16 + lg * 4 + j) * Nn +
                          col0 + wc * 64 + lr;
      if constexpr (BF16OUT) {
        unsigned short* cr = (unsigned short*)Cout + roff;
#pragma unroll
        for (int n = 0; n < 4; ++n) cr[n * 16] = f2bf(acc[m][n][j]);
      } else {
        float* cr = (float*)Cout + roff;
#pragma unroll
        for (int n = 0; n < 4; ++n) cr[n * 16] = acc[m][n][j];
      }
    }
}

// ----------------------------------------------------------------- RoPE ----
// q,k rows of qkv bf16 -> q bf16 (scaled by QSCALE), k bf16, (B,H,S,D).
__global__ __launch_bounds__(256) void rope_qk(
    const unsigned short* __restrict__ qkv, const float* __restrict__ cosT,
    const float* __restrict__ sinT, unsigned short* __restrict__ qb,
    unsigned short* __restrict__ kbuf) {
  const int row = blockIdx.x * 4 + (threadIdx.x >> 6);   // 0 .. B*S*24-1
  const int d = threadIdx.x & 63;
  const int hh = row % 24;
  const int bs = row / 24;
  const int s = bs & (SEQ - 1);
  const int b = bs >> 11;
  float v = bf2f(qkv[(size_t)bs * QKV_N + hh * 64 + d]);
  float partner = __shfl_xor(v, 32, 64);
  float rot = (d < 32) ? -partner : partner;
  v = v * cosT[s * 64 + d] + rot * sinT[s * 64 + d];
  if (hh < 12)
    qb[(((size_t)b * HEADS + hh) * SEQ + s) * DH + d] = f2bf(v * QSCALE);
  else
    kbuf[(((size_t)b * HEADS + (hh - 12)) * SEQ + s) * DH + d] = f2bf(v);
}

// V transpose through padded LDS: qkv bf16 (B*S, ...) -> v bf16 (B,H,D,S).
__global__ __launch_bounds__(256) void v_trans(
    const unsigned short* __restrict__ qkv, unsigned short* __restrict__ vT) {
  __shared__ unsigned short tile[64][65];
  const int bh = blockIdx.x;               // b*HEADS+h
  const int s0 = blockIdx.y * 64;
  const int b = bh / HEADS, h = bh % HEADS;
  const unsigned short* src = qkv + ((size_t)(b * SEQ + s0)) * QKV_N + (24 + h) * 64;
  const int d = threadIdx.x & 63, sg = threadIdx.x >> 6;
#pragma unroll
  for (int i = 0; i < 16; ++i) {
    int s = sg * 16 + i;
    tile[s][d] = src[(size_t)s * QKV_N + d];
  }
  __syncthreads();
  unsigned short* dst = vT + (size_t)bh * DH * SEQ + s0;
  const int sl = threadIdx.x & 63, dg = threadIdx.x >> 6;
#pragma unroll
  for (int i = 0; i < 16; ++i) {
    int dd = dg * 16 + i;
    dst[(size_t)dd * SEQ + sl] = tile[sl][dd];
  }
}

// ------------------------------------------------------------ attention ----
// KV-split flash attention. One wave per (16 q-rows, 512-key chunk).
// Swapped QK^T: ST[key][q] = mfma(Kfrag, Qfrag). Scores pre-scaled by
// log2(e)/8 (folded into Q). Online softmax in exp2 domain with defer-max;
// P re-layout via permlane register transpose. Writes unnormalized bf16
// partial acc + per-row (m,l).
__global__ __launch_bounds__(256) void attn_fused(
    const unsigned short* __restrict__ qb, const unsigned short* __restrict__ kbuf,
    const unsigned short* __restrict__ vT, unsigned short* __restrict__ ctxp,
    float2* __restrict__ ml) {
  const int lane = threadIdx.x & 63, wid = threadIdx.x >> 6;
  const int tid = blockIdx.x * 4 + wid;        // 0 .. 12287
  const int sp = tid & 3;
  const int qt = (tid >> 2) & 127;
  const int bh = tid >> 9;
  const int lr = lane & 15, lg = lane >> 4;

  const unsigned short* qp = qb + ((size_t)bh * SEQ + qt * 16 + lr) * DH + lg * 8;
  bf16x8 qf0 = ld8(qp);
  bf16x8 qf1 = ld8(qp + 32);
  const unsigned short* kbase = kbuf + (size_t)bh * SEQ * DH + lg * 8;
  const unsigned short* vbase = vT + (size_t)bh * DH * SEQ + lg * 8;

  f32x4 acc0 = {0,0,0,0}, acc1 = {0,0,0,0}, acc2 = {0,0,0,0}, acc3 = {0,0,0,0};
  float m = -1e30f, l = 0.f;

  for (int k0 = sp * KCHUNK; k0 < sp * KCHUNK + KCHUNK; k0 += 32) {
    const unsigned short* kp = kbase + (size_t)(k0 + lr) * DH;
    f32x4 st0 = {0,0,0,0}, st1 = {0,0,0,0};
    __builtin_amdgcn_s_setprio(1);
    st0 = __builtin_amdgcn_mfma_f32_16x16x32_bf16(ld8(kp),           qf0, st0, 0,0,0);
    st0 = __builtin_amdgcn_mfma_f32_16x16x32_bf16(ld8(kp + 32),      qf1, st0, 0,0,0);
    st1 = __builtin_amdgcn_mfma_f32_16x16x32_bf16(ld8(kp + 16*DH),   qf0, st1, 0,0,0);
    st1 = __builtin_amdgcn_mfma_f32_16x16x32_bf16(ld8(kp + 16*DH+32),qf1, st1, 0,0,0);
    __builtin_amdgcn_s_setprio(0);

    // per-q-column max over 32 keys: 7 fmax + 2 permlane butterflies
    float tmax = fmaxf(fmaxf(fmaxf(st0[0], st0[1]), fmaxf(st0[2], st0[3])),
                       fmaxf(fmaxf(st1[0], st1[1]), fmaxf(st1[2], st1[3])));
    tmax = red16max(red32max(tmax));

    if (tmax > m + 11.0f) {   // defer-max: rescale only on real growth
      float fac = exp2f(m - tmax);
      m = tmax;
      l *= fac;
      acc0 *= fac; acc1 *= fac; acc2 *= fac; acc3 *= fac;
    }

    float pa[4], pb[4];
#pragma unroll
    for (int r = 0; r < 4; ++r) {
      pa[r] = exp2f(st0[r] - m);
      pb[r] = exp2f(st1[r] - m);
    }
    float ls = ((pa[0] + pa[1]) + (pa[2] + pa[3])) +
               ((pb[0] + pb[1]) + (pb[2] + pb[3]));
    l += red16sum(red32sum(ls));

    // Register transpose into the PV B-fragment layout.
    unsigned c0 = pack2bf(pa[0], pa[1]);
    unsigned c1 = pack2bf(pa[2], pa[3]);
    unsigned c2 = pack2bf(pb[0], pb[1]);
    unsigned c3 = pack2bf(pb[2], pb[3]);
    pl32swap(c0, c2);  // reg-pair bit <-> lane bit5
    pl32swap(c1, c3);
    pl16swap(c0, c2);  // reg-pair bit <-> lane bit4
    pl16swap(c1, c3);
    u32x4 pw = {c0, c1, c2, c3};           // lane lg holds keys 8lg..8lg+7
    bf16x8 pf = __builtin_bit_cast(bf16x8, pw);

    __builtin_amdgcn_s_setprio(1);
    acc0 = __builtin_amdgcn_mfma_f32_16x16x32_bf16(ld8(vbase + (size_t)(     lr) * SEQ + k0), pf, acc0, 0,0,0);
    acc1 = __builtin_amdgcn_mfma_f32_16x16x32_bf16(ld8(vbase + (size_t)(16 + lr) * SEQ + k0), pf, acc1, 0,0,0);
    acc2 = __builtin_amdgcn_mfma_f32_16x16x32_bf16(ld8(vbase + (size_t)(32 + lr) * SEQ + k0), pf, acc2, 0,0,0);
    acc3 = __builtin_amdgcn_mfma_f32_16x16x32_bf16(ld8(vbase + (size_t)(48 + lr) * SEQ + k0), pf, acc3, 0,0,0);
    __builtin_amdgcn_s_setprio(0);
  }

  // unnormalized bf16 partial + (m,l)
  unsigned short* pp = ctxp +
      (((size_t)(sp * BH + bh)) * SEQ + qt * 16 + lr) * DH + 4 * lg;
  short4v o0, o1, o2, o3;
#pragma unroll
  for (int r = 0; r < 4; ++r) {
    o0[r] = (short)f2bf(acc0[r]);
    o1[r] = (short)f2bf(acc1[r]);
    o2[r] = (short)f2bf(acc2[r]);
    o3[r] = (short)f2bf(acc3[r]);
  }
  *reinterpret_cast<short4v*>(pp)      = o0;
  *reinterpret_cast<short4v*>(pp + 16) = o1;
  *reinterpret_cast<short4v*>(pp + 32) = o2;
  *reinterpret_cast<short4v*>(pp + 48) = o3;
  if (lane < 16) {
    float2 v; v.x = m; v.y = l;
    ml[(size_t)sp * (BH * SEQ) + bh * SEQ + qt * 16 + lr] = v;
  }
}

// combine the NSPLIT partials -> ctx bf16 (B*S, 768)
__global__ __launch_bounds__(256) void attn_combine(
    const unsigned short* __restrict__ ctxp, const float2* __restrict__ ml,
    unsigned short* __restrict__ ctx) {
  const int idx = blockIdx.x * 256 + threadIdx.x;  // over BH*SEQ*DH
  const int d = idx & 63;
  const int row = idx >> 6;                        // bh*SEQ + s
  float m0 = ml[row].x,                 l0 = ml[row].y;
  float m1 = ml[row + BH*SEQ].x,        l1 = ml[row + BH*SEQ].y;
  float m2 = ml[row + 2*BH*SEQ].x,      l2 = ml[row + 2*BH*SEQ].y;
  float m3 = ml[row + 3*BH*SEQ].x,      l3 = ml[row + 3*BH*SEQ].y;
  float M = fmaxf(fmaxf(m0, m1), fmaxf(m2, m3));
  float w0 = exp2f(m0 - M), w1 = exp2f(m1 - M);
  float w2 = exp2f(m2 - M), w3 = exp2f(m3 - M);
  float den = w0 * l0 + w1 * l1 + w2 * l2 + w3 * l3;
  const size_t pstride = (size_t)BH * SEQ * DH;
  float num = w0 * bf2f(ctxp[(size_t)row * DH + d]) +
              w1 * bf2f(ctxp[(size_t)row * DH + d + pstride]) +
              w2 * bf2f(ctxp[(size_t)row * DH + d + 2 * pstride]) +
              w3 * bf2f(ctxp[(size_t)row * DH + d + 3 * pstride]);
  const int bh = row >> 11, s = row & (SEQ - 1);
  const int b = bh / HEADS, h = bh % HEADS;
  ctx[((size_t)(b * SEQ + s)) * CDIM + h * DH + d] = f2bf(num / den);
}

// ---------------------------------------------------------- add+rmsnorm ----
__global__ __launch_bounds__(256) void add_rmsnorm(
    const float* __restrict__ a, const float* __restrict__ b,
    float* __restrict__ outf, unsigned short* __restrict__ outb) {
  const int row = blockIdx.x;
  const int tid = threadIdx.x;
  const float* ap = a + (size_t)row * CDIM;
  const float* bp = b + (size_t)row * CDIM;
  float v0 = ap[tid]       + bp[tid];
  float v1 = ap[tid + 256] + bp[tid + 256];
  float v2 = ap[tid + 512] + bp[tid + 512];
  float ss = v0 * v0 + v1 * v1 + v2 * v2;
#pragma unroll
  for (int off = 32; off > 0; off >>= 1) ss += __shfl_xor(ss, off, 64);
  __shared__ float red[4];
  if ((tid & 63) == 0) red[tid >> 6] = ss;
  __syncthreads();
  float tot = red[0] + red[1] + red[2] + red[3];
  float r = rsqrtf(tot * (1.f / 768.f) + 1e-5f);
  float* of = outf + (size_t)row * CDIM;
  of[tid]       = v0 * r;
  of[tid + 256] = v1 * r;
  of[tid + 512] = v2 * r;
  if (outb) {
    unsigned short* ob = outb + (size_t)row * CDIM;
    ob[tid]       = f2bf(v0 * r);
    ob[tid + 256] = f2bf(v1 * r);
    ob[tid + 512] = f2bf(v2 * r);
  }
}

// ------------------------------------------------------------- silu*mul ----
__global__ __launch_bounds__(256) void silu_mul(
    const unsigned short* __restrict__ gu, unsigned short* __restrict__ hb) {
  const int i = blockIdx.x * 256 + threadIdx.x;  // < MROWS*INTER
  const int s = i >> 11, c = i & (INTER - 1);
  float g = bf2f(gu[(size_t)s * GU_N + c]);
  float u = bf2f(gu[(size_t)s * GU_N + INTER + c]);
  float sig = 1.f / (1.f + __expf(-g));
  hb[i] = f2bf(g * sig * u);
}

// ----------------------------------------------------------------- host ----
extern "C" void kernel_launch(void* const* d_in, const int* in_sizes, int n_in,
                              void* d_out, int out_size, void* d_ws, size_t ws_size,
                              hipStream_t stream) {
  const float* hidden = (const float*)d_in[0];
  const float* cosT   = (const float*)d_in[1];
  const float* sinT   = (const float*)d_in[2];
  const float* wqkv   = (const float*)d_in[3];
  const float* wo     = (const float*)d_in[4];
  const float* wgu    = (const float*)d_in[5];
  const float* wd     = (const float*)d_in[6];
  float* out = (float*)d_out;

  char* wsp = (char*)d_ws;
  size_t off = 0;
  auto alloc = [&](size_t bytes) { void* p = wsp + off; off += bytes; return p; };

  // persistent
  unsigned short* wqkvb = (unsigned short*)alloc(2ull * 1769472);
  unsigned short* wob   = (unsigned short*)alloc(2ull * 589824);
  unsigned short* wgub  = (unsigned short*)alloc(2ull * 3145728);
  unsigned short* wdb   = (unsigned short*)alloc(2ull * 1572864);
  unsigned short* hb    = (unsigned short*)alloc(2ull * 3145728);
  float*          x     = (float*)alloc(4ull * 3145728);
  unsigned short* xb    = (unsigned short*)alloc(2ull * 3145728);
  const size_t roff = off;

  // phase A (through attention)
  unsigned short* qkvb = (unsigned short*)alloc(2ull * MROWS * QKV_N);
  unsigned short* qB   = (unsigned short*)alloc(2ull * MROWS * CDIM);
  unsigned short* kB   = (unsigned short*)alloc(2ull * MROWS * CDIM);
  unsigned short* vTb  = (unsigned short*)alloc(2ull * MROWS * CDIM);
  unsigned short* ctx  = (unsigned short*)alloc(2ull * MROWS * CDIM);
  float*          attn = (float*)alloc(4ull * MROWS * CDIM);
  unsigned short* ctxp = (unsigned short*)alloc(2ull * NSPLIT * BH * SEQ * DH);
  float2*         ml   = (float2*)alloc(8ull * NSPLIT * BH * SEQ);

  // phase B (MLP) aliases phase A
  off = roff;
  unsigned short* gub  = (unsigned short*)alloc(2ull * MROWS * GU_N);
  unsigned short* hmid = (unsigned short*)alloc(2ull * MROWS * INTER);
  float*          mlp  = (float*)alloc(4ull * MROWS * CDIM);
  (void)ws_size; (void)in_sizes; (void)n_in; (void)out_size;

  // 1. casts
  cast_all<<<2048, 256, 0, stream>>>(hidden, wqkv, wo, wgu, wd,
                                     hb, wqkvb, wob, wgub, wdb);
  // 2. qkv = hidden @ w_qkv^T (bf16 out)
  gemm_lds<true><<<dim3(QKV_N / 128, MROWS / 128), 256, 0, stream>>>(
      hb, wqkvb, qkvb, MROWS, QKV_N, CDIM);
  // 3. rope (q,k) + v transpose
  rope_qk<<<(MROWS * 24) / 4, 256, 0, stream>>>(qkvb, cosT, sinT, qB, kB);
  v_trans<<<dim3(BH, SEQ / 64), 256, 0, stream>>>(qkvb, vTb);
  // 4. attention (KV-split) + combine
  attn_fused<<<(BH * (SEQ / 16) * NSPLIT) / 4, 256, 0, stream>>>(
      qB, kB, vTb, ctxp, ml);
  attn_combine<<<(BH * SEQ * DH) / 256, 256, 0, stream>>>(ctxp, ml, ctx);
  // 5. attn_out = ctx @ w_o^T
  gemm_lds<false><<<dim3(CDIM / 128, MROWS / 128), 256, 0, stream>>>(
      ctx, wob, attn, MROWS, CDIM, CDIM);
  // 6. x = rmsnorm(hidden + attn)
  add_rmsnorm<<<MROWS, 256, 0, stream>>>(hidden, attn, x, xb);
  // 7. gu = x @ w_gate_up^T (bf16 out)
  gemm_lds<true><<<dim3(GU_N / 128, MROWS / 128), 256, 0, stream>>>(
      xb, wgub, gub, MROWS, GU_N, CDIM);
  // 8. h = silu(gate)*up
  silu_mul<<<(MROWS * INTER) / 256, 256, 0, stream>>>(gub, hmid);
  // 9. mlp = h @ w_down^T
  gemm_lds<false><<<dim3(CDIM / 128, MROWS / 128), 256, 0, stream>>>(
      hmid, wdb, mlp, MROWS, CDIM, INTER);
  // 10. out = rmsnorm(x + mlp)
  add_rmsnorm<<<MROWS, 256, 0, stream>>>(x, mlp, out, nullptr);
}

// Round 7
// 363.410 us; speedup vs baseline: 1.2697x; 1.2697x over previous
//
#include <hip/hip_runtime.h>

// EBT transformer block on MI355X. All GEMMs via mfma_f32_16x16x32_bf16
// (fp32 accumulate) with global_load_lds staging (m97 structure);
// flash attention with KV-split=4, swapped QK^T, permlane softmax,
// and FRAGMENT-ORDER TILED Q/K/V global layouts so every attention
// load is a lane-contiguous 1KB transaction (no 16-row scatter).

typedef __attribute__((ext_vector_type(8))) __bf16 bf16x8;
typedef __attribute__((ext_vector_type(8))) short short8;
typedef __attribute__((ext_vector_type(4))) short short4v;
typedef __attribute__((ext_vector_type(4))) float f32x4;
typedef __attribute__((ext_vector_type(4))) float float4v;
typedef __attribute__((ext_vector_type(4))) unsigned int u32x4;

#define CDIM   768
#define HEADS  12
#define DH     64
#define SEQ    2048
#define BATCH  2
#define MROWS  4096      // B*S
#define QKV_N  2304      // 3*H*D
#define INTER  2048
#define GU_N   4096      // 2*INTER
#define NSPLIT 4
#define KCHUNK (SEQ / NSPLIT)   // 512
#define BH     (BATCH * HEADS)  // 24

// log2(e)/8 folded into Q so scores are already in exp2 domain.
#define QSCALE 0.18033688011112043f

static __device__ __forceinline__ unsigned short f2bf(float f) {
  unsigned int u = __builtin_bit_cast(unsigned int, f);
  u += 0x7fffu + ((u >> 16) & 1u);
  return (unsigned short)(u >> 16);
}
static __device__ __forceinline__ float bf2f(unsigned short u) {
  return __builtin_bit_cast(float, ((unsigned int)u) << 16);
}

static __device__ __forceinline__ bf16x8 ld8(const unsigned short* p) {
  return __builtin_bit_cast(bf16x8, *reinterpret_cast<const short8*>(p));
}

static __device__ __forceinline__ unsigned pack2bf(float lo, float hi) {
  unsigned short a = __builtin_bit_cast(unsigned short, (__bf16)lo);
  unsigned short b = __builtin_bit_cast(unsigned short, (__bf16)hi);
  return (unsigned)a | ((unsigned)b << 16);
}

// register-transpose building block: exchange reg-pair bit with lane bit5/bit4
static __device__ __forceinline__ void pl32swap(unsigned& a, unsigned& b) {
  auto r = __builtin_amdgcn_permlane32_swap(a, b, false, false);
  a = r[0]; b = r[1];
}
static __device__ __forceinline__ void pl16swap(unsigned& a, unsigned& b) {
  auto r = __builtin_amdgcn_permlane16_swap(a, b, false, false);
  a = r[0]; b = r[1];
}
// butterfly reduce across lane bit5 / bit4: one permlane + one op
static __device__ __forceinline__ float red32max(float x) {
  unsigned xi = __builtin_bit_cast(unsigned, x);
  auto r = __builtin_amdgcn_permlane32_swap(xi, xi, false, false);
  return fmaxf(__builtin_bit_cast(float, r[0]), __builtin_bit_cast(float, r[1]));
}
static __device__ __forceinline__ float red16max(float x) {
  unsigned xi = __builtin_bit_cast(unsigned, x);
  auto r = __builtin_amdgcn_permlane16_swap(xi, xi, false, false);
  return fmaxf(__builtin_bit_cast(float, r[0]), __builtin_bit_cast(float, r[1]));
}
static __device__ __forceinline__ float red32sum(float x) {
  unsigned xi = __builtin_bit_cast(unsigned, x);
  auto r = __builtin_amdgcn_permlane32_swap(xi, xi, false, false);
  return __builtin_bit_cast(float, r[0]) + __builtin_bit_cast(float, r[1]);
}
static __device__ __forceinline__ float red16sum(float x) {
  unsigned xi = __builtin_bit_cast(unsigned, x);
  auto r = __builtin_amdgcn_permlane16_swap(xi, xi, false, false);
  return __builtin_bit_cast(float, r[0]) + __builtin_bit_cast(float, r[1]);
}

// ---------------------------------------------------------------- casts ----
__global__ __launch_bounds__(256) void cast_all(
    const float* __restrict__ h, const float* __restrict__ wqkv,
    const float* __restrict__ wo, const float* __restrict__ wgu,
    const float* __restrict__ wd,
    unsigned short* __restrict__ hb, unsigned short* __restrict__ wqkvb,
    unsigned short* __restrict__ wob, unsigned short* __restrict__ wgub,
    unsigned short* __restrict__ wdb) {
  const int n0 = 786432, n1 = 442368, n2 = 147456, n3 = 786432, n4 = 393216;
  const int total = n0 + n1 + n2 + n3 + n4;   // in float4 units
  for (int i = blockIdx.x * blockDim.x + threadIdx.x; i < total;
       i += gridDim.x * blockDim.x) {
    int j = i;
    const float* src; unsigned short* dst;
    if      (j < n0)            { src = h;    dst = hb;    }
    else if ((j -= n0) < n1)    { src = wqkv; dst = wqkvb; }
    else if ((j -= n1) < n2)    { src = wo;   dst = wob;   }
    else if ((j -= n2) < n3)    { src = wgu;  dst = wgub;  }
    else    { j -= n3;            src = wd;   dst = wdb;   }
    float4v v = *reinterpret_cast<const float4v*>(src + 4 * (size_t)j);
    short4v o;
#pragma unroll
    for (int e = 0; e < 4; ++e) o[e] = (short)f2bf(v[e]);
    *reinterpret_cast<short4v*>(dst + 4 * (size_t)j) = o;
  }
}

// ----------------------------------------------------------------- GEMM ----
// C[m][n] = sum_k A[m][k] * W[n][k].  128x128 block tile, BK=32, 4 waves,
// global_load_lds staging (m97 structure). Mm,Nn %128==0, Kk %32==0.
template <bool BF16OUT>
__global__ __launch_bounds__(256) void gemm_lds(
    const unsigned short* __restrict__ A, const unsigned short* __restrict__ W,
    void* __restrict__ Cout, int Mm, int Nn, int Kk) {
  __shared__ unsigned short Alds[4096];   // [128][32]
  __shared__ unsigned short Blds[4096];   // [128][32]
  const int t = threadIdx.x;
  const int lane = t & 63, w = t >> 6;
  const int lr = lane & 15, lg = lane >> 4;
  const int row0 = blockIdx.y * 128, col0 = blockIdx.x * 128;
  const int wr = w >> 1, wc = w & 1;

  const unsigned short* ga = A + (size_t)(row0 + (t >> 2)) * Kk + (t & 3) * 8;
  const unsigned short* gb = W + (size_t)(col0 + (t >> 2)) * Kk + (t & 3) * 8;
  const size_t g64 = (size_t)64 * Kk;
  unsigned short* la0 = Alds + w * 512;   // wave-uniform LDS base
  unsigned short* lb0 = Blds + w * 512;
  const unsigned short* ra = Alds + (wr * 64 + lr) * 32 + lg * 8;
  const unsigned short* rb = Blds + (wc * 64 + lr) * 32 + lg * 8;

  f32x4 acc[4][4] = {};
  for (int k0 = 0; k0 < Kk; k0 += 32) {
    __builtin_amdgcn_global_load_lds((const unsigned int*)(ga + k0),
                                     (unsigned int*)la0, 16, 0, 0);
    __builtin_amdgcn_global_load_lds((const unsigned int*)(ga + k0 + g64),
                                     (unsigned int*)(la0 + 2048), 16, 0, 0);
    __builtin_amdgcn_global_load_lds((const unsigned int*)(gb + k0),
                                     (unsigned int*)lb0, 16, 0, 0);
    __builtin_amdgcn_global_load_lds((const unsigned int*)(gb + k0 + g64),
                                     (unsigned int*)(lb0 + 2048), 16, 0, 0);
    __syncthreads();
    bf16x8 af[4], bfr[4];
#pragma unroll
    for (int m = 0; m < 4; ++m) af[m] = ld8(ra + m * 512);
#pragma unroll
    for (int n = 0; n < 4; ++n) bfr[n] = ld8(rb + n * 512);
    __builtin_amdgcn_s_setprio(1);
#pragma unroll
    for (int m = 0; m < 4; ++m)
#pragma unroll
      for (int n = 0; n < 4; ++n)
        acc[m][n] = __builtin_amdgcn_mfma_f32_16x16x32_bf16(af[m], bfr[n],
                                                            acc[m][n], 0, 0, 0);
    __builtin_amdgcn_s_setprio(0);
    __syncthreads();
  }
#pragma unroll
  for (int m = 0; m < 4; ++m)
#pragma unroll
    for (int j = 0; j < 4; ++j) {
      const size_t roff = (size_t)(row0 + wr * 64 + m * 16 + lg * 4 + j) * Nn +
                          col0 + wc * 64 + lr;
      if constexpr (BF16OUT) {
        unsigned short* cr = (unsigned short*)Cout + roff;
#pragma unroll
        for (int n = 0; n < 4; ++n) cr[n * 16] = f2bf(acc[m][n][j]);
      } else {
        float* cr = (float*)Cout + roff;
#pragma unroll
        for (int n = 0; n < 4; ++n) cr[n * 16] = acc[m][n][j];
      }
    }
}

// ----------------------------------------------------------------- RoPE ----
// q,k rows of qkv bf16 -> rope -> fragment-order tiles:
//   tile[bh][t=s/16][dh=d/32][lane=lg*16+lr][j]  (lr=s%16, lg=(d%32)/8, j=d%8)
// so a wave's MFMA fragment load is contiguous 1KB.
__global__ __launch_bounds__(256) void rope_qk(
    const unsigned short* __restrict__ qkv, const float* __restrict__ cosT,
    const float* __restrict__ sinT, unsigned short* __restrict__ qtile,
    unsigned short* __restrict__ ktile) {
  const int row = blockIdx.x * 4 + (threadIdx.x >> 6);   // 0 .. B*S*24-1
  const int d = threadIdx.x & 63;
  const int hh = row % 24;
  const int bs = row / 24;
  const int s = bs & (SEQ - 1);
  const int b = bs >> 11;
  float v = bf2f(qkv[(size_t)bs * QKV_N + hh * 64 + d]);
  float partner = __shfl_xor(v, 32, 64);
  float rot = (d < 32) ? -partner : partner;
  v = v * cosT[s * 64 + d] + rot * sinT[s * 64 + d];
  const int t = s >> 4, lr = s & 15;
  const int dh = d >> 5, lg = (d & 31) >> 3, j = d & 7;
  if (hh < 12) {
    const int bh = b * HEADS + hh;
    qtile[((size_t)(bh * 128 + t) * 2 + dh) * 512 + (lg * 16 + lr) * 8 + j] =
        f2bf(v * QSCALE);
  } else {
    const int bh = b * HEADS + (hh - 12);
    ktile[((size_t)(bh * 128 + t) * 2 + dh) * 512 + (lg * 16 + lr) * 8 + j] =
        f2bf(v);
  }
}

// V transpose through padded LDS -> fragment-order tiles:
//   vtile[bh][k32=k/32][d0=d/16][lane=lg*16+lr][j]  holds V[k32*32+lg*8+j][d0*16+lr]
__global__ __launch_bounds__(256) void v_trans(
    const unsigned short* __restrict__ qkv, unsigned short* __restrict__ vT) {
  __shared__ unsigned short tile[64][66];
  const int bh = blockIdx.x;               // b*HEADS+h
  const int s0 = blockIdx.y * 64;
  const int b = bh / HEADS, h = bh % HEADS;
  const unsigned short* src = qkv + ((size_t)(b * SEQ + s0)) * QKV_N + (24 + h) * 64;
  const int d = threadIdx.x & 63, sg = threadIdx.x >> 6;
#pragma unroll
  for (int i = 0; i < 16; ++i) {
    int s = sg * 16 + i;
    tile[s][d] = src[(size_t)s * QKV_N + d];
  }
  __syncthreads();
  const int lane = threadIdx.x & 63, wid = threadIdx.x >> 6;
  const int lr = lane & 15, lg = lane >> 4;
  unsigned short* dst = vT + ((size_t)bh * 64 + (s0 >> 5)) * 4 * 512;
#pragma unroll
  for (int tt = 0; tt < 2; ++tt) {
    const int ti = wid * 2 + tt;          // 0..7: kt = ti>>2, d0q = ti&3
    const int kt = ti >> 2, d0 = (ti & 3) * 16;
    short8 o;
#pragma unroll
    for (int j = 0; j < 8; ++j)
      o[j] = (short)tile[kt * 32 + lg * 8 + j][d0 + lr];
    *reinterpret_cast<short8*>(dst + ((size_t)kt * 4 + (ti & 3)) * 512 +
                               lane * 8) = o;
  }
}

// ------------------------------------------------------------ attention ----
// KV-split flash attention, fragment-order tiled inputs: every global load
// is a contiguous 1KB wave transaction. One wave per (16 q-rows, 512 keys).
__global__ __launch_bounds__(256) void attn_fused(
    const unsigned short* __restrict__ qtile, const unsigned short* __restrict__ ktile,
    const unsigned short* __restrict__ vtile, unsigned short* __restrict__ ctxp,
    float2* __restrict__ ml) {
  const int lane = threadIdx.x & 63, wid = threadIdx.x >> 6;
  const int tid = blockIdx.x * 4 + wid;        // 0 .. 12287
  const int sp = tid & 3;
  const int qt = (tid >> 2) & 127;
  const int bh = tid >> 9;
  const int lr = lane & 15, lg = lane >> 4;

  const unsigned short* qp =
      qtile + ((size_t)(bh * 128 + qt) * 2) * 512 + lane * 8;
  bf16x8 qf0 = ld8(qp);
  bf16x8 qf1 = ld8(qp + 512);
  const unsigned short* kb = ktile + (size_t)bh * 128 * 2 * 512 + lane * 8;
  const unsigned short* vb = vtile + (size_t)bh * 64 * 4 * 512 + lane * 8;

  f32x4 acc0 = {0,0,0,0}, acc1 = {0,0,0,0}, acc2 = {0,0,0,0}, acc3 = {0,0,0,0};
  float m = -1e30f, l = 0.f;

  for (int k0 = sp * KCHUNK; k0 < sp * KCHUNK + KCHUNK; k0 += 32) {
    const unsigned short* kp = kb + (size_t)(k0 >> 4) * 1024;
    f32x4 st0 = {0,0,0,0}, st1 = {0,0,0,0};
    __builtin_amdgcn_s_setprio(1);
    st0 = __builtin_amdgcn_mfma_f32_16x16x32_bf16(ld8(kp),        qf0, st0, 0,0,0);
    st0 = __builtin_amdgcn_mfma_f32_16x16x32_bf16(ld8(kp + 512),  qf1, st0, 0,0,0);
    st1 = __builtin_amdgcn_mfma_f32_16x16x32_bf16(ld8(kp + 1024), qf0, st1, 0,0,0);
    st1 = __builtin_amdgcn_mfma_f32_16x16x32_bf16(ld8(kp + 1536), qf1, st1, 0,0,0);
    __builtin_amdgcn_s_setprio(0);

    // per-q-column max over 32 keys: 7 fmax + 2 permlane butterflies
    float tmax = fmaxf(fmaxf(fmaxf(st0[0], st0[1]), fmaxf(st0[2], st0[3])),
                       fmaxf(fmaxf(st1[0], st1[1]), fmaxf(st1[2], st1[3])));
    tmax = red16max(red32max(tmax));

    if (tmax > m + 11.0f) {   // defer-max: rescale only on real growth
      float fac = exp2f(m - tmax);
      m = tmax;
      l *= fac;
      acc0 *= fac; acc1 *= fac; acc2 *= fac; acc3 *= fac;
    }

    float pa[4], pb[4];
#pragma unroll
    for (int r = 0; r < 4; ++r) {
      pa[r] = exp2f(st0[r] - m);
      pb[r] = exp2f(st1[r] - m);
    }
    float ls = ((pa[0] + pa[1]) + (pa[2] + pa[3])) +
               ((pb[0] + pb[1]) + (pb[2] + pb[3]));
    l += red16sum(red32sum(ls));

    // Register transpose into the PV B-fragment layout.
    unsigned c0 = pack2bf(pa[0], pa[1]);
    unsigned c1 = pack2bf(pa[2], pa[3]);
    unsigned c2 = pack2bf(pb[0], pb[1]);
    unsigned c3 = pack2bf(pb[2], pb[3]);
    pl32swap(c0, c2);  // reg-pair bit <-> lane bit5
    pl32swap(c1, c3);
    pl16swap(c0, c2);  // reg-pair bit <-> lane bit4
    pl16swap(c1, c3);
    u32x4 pw = {c0, c1, c2, c3};           // lane lg holds keys 8lg..8lg+7
    bf16x8 pf = __builtin_bit_cast(bf16x8, pw);

    const unsigned short* vp = vb + (size_t)(k0 >> 5) * 2048;
    __builtin_amdgcn_s_setprio(1);
    acc0 = __builtin_amdgcn_mfma_f32_16x16x32_bf16(ld8(vp),        pf, acc0, 0,0,0);
    acc1 = __builtin_amdgcn_mfma_f32_16x16x32_bf16(ld8(vp + 512),  pf, acc1, 0,0,0);
    acc2 = __builtin_amdgcn_mfma_f32_16x16x32_bf16(ld8(vp + 1024), pf, acc2, 0,0,0);
    acc3 = __builtin_amdgcn_mfma_f32_16x16x32_bf16(ld8(vp + 1536), pf, acc3, 0,0,0);
    __builtin_amdgcn_s_setprio(0);
  }

  // unnormalized bf16 partial + (m,l)
  unsigned short* pp = ctxp +
      (((size_t)(sp * BH + bh)) * SEQ + qt * 16 + lr) * DH + 4 * lg;
  short4v o0, o1, o2, o3;
#pragma unroll
  for (int r = 0; r < 4; ++r) {
    o0[r] = (short)f2bf(acc0[r]);
    o1[r] = (short)f2bf(acc1[r]);
    o2[r] = (short)f2bf(acc2[r]);
    o3[r] = (short)f2bf(acc3[r]);
  }
  *reinterpret_cast<short4v*>(pp)      = o0;
  *reinterpret_cast<short4v*>(pp + 16) = o1;
  *reinterpret_cast<short4v*>(pp + 32) = o2;
  *reinterpret_cast<short4v*>(pp + 48) = o3;
  if (lane < 16) {
    float2 v; v.x = m; v.y = l;
    ml[(size_t)sp * (BH * SEQ) + bh * SEQ + qt * 16 + lr] = v;
  }
}

// combine the NSPLIT partials -> ctx bf16 (B*S, 768)
__global__ __launch_bounds__(256) void attn_combine(
    const unsigned short* __restrict__ ctxp, const float2* __restrict__ ml,
    unsigned short* __restrict__ ctx) {
  const int idx = blockIdx.x * 256 + threadIdx.x;  // over BH*SEQ*DH
  const int d = idx & 63;
  const int row = idx >> 6;                        // bh*SEQ + s
  float m0 = ml[row].x,                 l0 = ml[row].y;
  float m1 = ml[row + BH*SEQ].x,        l1 = ml[row + BH*SEQ].y;
  float m2 = ml[row + 2*BH*SEQ].x,      l2 = ml[row + 2*BH*SEQ].y;
  float m3 = ml[row + 3*BH*SEQ].x,      l3 = ml[row + 3*BH*SEQ].y;
  float M = fmaxf(fmaxf(m0, m1), fmaxf(m2, m3));
  float w0 = exp2f(m0 - M), w1 = exp2f(m1 - M);
  float w2 = exp2f(m2 - M), w3 = exp2f(m3 - M);
  float den = w0 * l0 + w1 * l1 + w2 * l2 + w3 * l3;
  const size_t pstride = (size_t)BH * SEQ * DH;
  float num = w0 * bf2f(ctxp[(size_t)row * DH + d]) +
              w1 * bf2f(ctxp[(size_t)row * DH + d + pstride]) +
              w2 * bf2f(ctxp[(size_t)row * DH + d + 2 * pstride]) +
              w3 * bf2f(ctxp[(size_t)row * DH + d + 3 * pstride]);
  const int bh = row >> 11, s = row & (SEQ - 1);
  const int b = bh / HEADS, h = bh % HEADS;
  ctx[((size_t)(b * SEQ + s)) * CDIM + h * DH + d] = f2bf(num / den);
}

// ---------------------------------------------------------- add+rmsnorm ----
__global__ __launch_bounds__(256) void add_rmsnorm(
    const float* __restrict__ a, const float* __restrict__ b,
    float* __restrict__ outf, unsigned short* __restrict__ outb) {
  const int row = blockIdx.x;
  const int tid = threadIdx.x;
  const float* ap = a + (size_t)row * CDIM;
  const float* bp = b + (size_t)row * CDIM;
  float v0 = ap[tid]       + bp[tid];
  float v1 = ap[tid + 256] + bp[tid + 256];
  float v2 = ap[tid + 512] + bp[tid + 512];
  float ss = v0 * v0 + v1 * v1 + v2 * v2;
#pragma unroll
  for (int off = 32; off > 0; off >>= 1) ss += __shfl_xor(ss, off, 64);
  __shared__ float red[4];
  if ((tid & 63) == 0) red[tid >> 6] = ss;
  __syncthreads();
  float tot = red[0] + red[1] + red[2] + red[3];
  float r = rsqrtf(tot * (1.f / 768.f) + 1e-5f);
  float* of = outf + (size_t)row * CDIM;
  of[tid]       = v0 * r;
  of[tid + 256] = v1 * r;
  of[tid + 512] = v2 * r;
  if (outb) {
    unsigned short* ob = outb + (size_t)row * CDIM;
    ob[tid]       = f2bf(v0 * r);
    ob[tid + 256] = f2bf(v1 * r);
    ob[tid + 512] = f2bf(v2 * r);
  }
}

// ------------------------------------------------------------- silu*mul ----
__global__ __launch_bounds__(256) void silu_mul(
    const unsigned short* __restrict__ gu, unsigned short* __restrict__ hb) {
  const int i = blockIdx.x * 256 + threadIdx.x;  // < MROWS*INTER
  const int s = i >> 11, c = i & (INTER - 1);
  float g = bf2f(gu[(size_t)s * GU_N + c]);
  float u = bf2f(gu[(size_t)s * GU_N + INTER + c]);
  float sig = 1.f / (1.f + __expf(-g));
  hb[i] = f2bf(g * sig * u);
}

// ----------------------------------------------------------------- host ----
extern "C" void kernel_launch(void* const* d_in, const int* in_sizes, int n_in,
                              void* d_out, int out_size, void* d_ws, size_t ws_size,
                              hipStream_t stream) {
  const float* hidden = (const float*)d_in[0];
  const float* cosT   = (const float*)d_in[1];
  const float* sinT   = (const float*)d_in[2];
  const float* wqkv   = (const float*)d_in[3];
  const float* wo     = (const float*)d_in[4];
  const float* wgu    = (const float*)d_in[5];
  const float* wd     = (const float*)d_in[6];
  float* out = (float*)d_out;

  char* wsp = (char*)d_ws;
  size_t off = 0;
  auto alloc = [&](size_t bytes) { void* p = wsp + off; off += bytes; return p; };

  // persistent
  unsigned short* wqkvb = (unsigned short*)alloc(2ull * 1769472);
  unsigned short* wob   = (unsigned short*)alloc(2ull * 589824);
  unsigned short* wgub  = (unsigned short*)alloc(2ull * 3145728);
  unsigned short* wdb   = (unsigned short*)alloc(2ull * 1572864);
  unsigned short* hb    = (unsigned short*)alloc(2ull * 3145728);
  float*          x     = (float*)alloc(4ull * 3145728);
  unsigned short* xb    = (unsigned short*)alloc(2ull * 3145728);
  const size_t roff = off;

  // phase A (through attention)
  unsigned short* qkvb = (unsigned short*)alloc(2ull * MROWS * QKV_N);
  unsigned short* qT   = (unsigned short*)alloc(2ull * MROWS * CDIM);
  unsigned short* kT   = (unsigned short*)alloc(2ull * MROWS * CDIM);
  unsigned short* vTb  = (unsigned short*)alloc(2ull * MROWS * CDIM);
  unsigned short* ctx  = (unsigned short*)alloc(2ull * MROWS * CDIM);
  float*          attn = (float*)alloc(4ull * MROWS * CDIM);
  unsigned short* ctxp = (unsigned short*)alloc(2ull * NSPLIT * BH * SEQ * DH);
  float2*         ml   = (float2*)alloc(8ull * NSPLIT * BH * SEQ);

  // phase B (MLP) aliases phase A
  off = roff;
  unsigned short* gub  = (unsigned short*)alloc(2ull * MROWS * GU_N);
  unsigned short* hmid = (unsigned short*)alloc(2ull * MROWS * INTER);
  float*          mlp  = (float*)alloc(4ull * MROWS * CDIM);
  (void)ws_size; (void)in_sizes; (void)n_in; (void)out_size;

  // 1. casts
  cast_all<<<2048, 256, 0, stream>>>(hidden, wqkv, wo, wgu, wd,
                                     hb, wqkvb, wob, wgub, wdb);
  // 2. qkv = hidden @ w_qkv^T (bf16 out)
  gemm_lds<true><<<dim3(QKV_N / 128, MROWS / 128), 256, 0, stream>>>(
      hb, wqkvb, qkvb, MROWS, QKV_N, CDIM);
  // 3. rope (q,k) + v transpose into fragment-order tiles
  rope_qk<<<(MROWS * 24) / 4, 256, 0, stream>>>(qkvb, cosT, sinT, qT, kT);
  v_trans<<<dim3(BH, SEQ / 64), 256, 0, stream>>>(qkvb, vTb);
  // 4. attention (KV-split) + combine
  attn_fused<<<(BH * (SEQ / 16) * NSPLIT) / 4, 256, 0, stream>>>(
      qT, kT, vTb, ctxp, ml);
  attn_combine<<<(BH * SEQ * DH) / 256, 256, 0, stream>>>(ctxp, ml, ctx);
  // 5. attn_out = ctx @ w_o^T
  gemm_lds<false><<<dim3(CDIM / 128, MROWS / 128), 256, 0, stream>>>(
      ctx, wob, attn, MROWS, CDIM, CDIM);
  // 6. x = rmsnorm(hidden + attn)
  add_rmsnorm<<<MROWS, 256, 0, stream>>>(hidden, attn, x, xb);
  // 7. gu = x @ w_gate_up^T (bf16 out)
  gemm_lds<true><<<dim3(GU_N / 128, MROWS / 128), 256, 0, stream>>>(
      xb, wgub, gub, MROWS, GU_N, CDIM);
  // 8. h = silu(gate)*up
  silu_mul<<<(MROWS * INTER) / 256, 256, 0, stream>>>(gub, hmid);
  // 9. mlp = h @ w_down^T
  gemm_lds<false><<<dim3(CDIM / 128, MROWS / 128), 256, 0, stream>>>(
      hmid, wdb, mlp, MROWS, CDIM, INTER);
  // 10. out = rmsnorm(x + mlp)
  add_rmsnorm<<<MROWS, 256, 0, stream>>>(x, mlp, out, nullptr);
}

// Round 8
// 349.418 us; speedup vs baseline: 1.3206x; 1.0400x over previous
//
#include <hip/hip_runtime.h>

// EBT transformer block on MI355X. All GEMMs via mfma_f32_16x16x32_bf16
// (fp32 accumulate) with global_load_lds staging; flash attention with
// KV-split=4, fragment-order tiled Q/K/V, swapped QK^T, permlane softmax
// with raw v_exp_f32 / v_cvt_pk_bf16_f32 and deferred l-reduction.

typedef __attribute__((ext_vector_type(8))) __bf16 bf16x8;
typedef __attribute__((ext_vector_type(8))) short short8;
typedef __attribute__((ext_vector_type(4))) short short4v;
typedef __attribute__((ext_vector_type(4))) float f32x4;
typedef __attribute__((ext_vector_type(4))) float float4v;
typedef __attribute__((ext_vector_type(4))) unsigned int u32x4;

#define CDIM   768
#define HEADS  12
#define DH     64
#define SEQ    2048
#define BATCH  2
#define MROWS  4096      // B*S
#define QKV_N  2304      // 3*H*D
#define INTER  2048
#define GU_N   4096      // 2*INTER
#define NSPLIT 4
#define KCHUNK (SEQ / NSPLIT)   // 512
#define BH     (BATCH * HEADS)  // 24

// log2(e)/8 folded into Q so scores are already in exp2 domain.
#define QSCALE 0.18033688011112043f

static __device__ __forceinline__ unsigned short f2bf(float f) {
  unsigned int u = __builtin_bit_cast(unsigned int, f);
  u += 0x7fffu + ((u >> 16) & 1u);
  return (unsigned short)(u >> 16);
}
static __device__ __forceinline__ float bf2f(unsigned short u) {
  return __builtin_bit_cast(float, ((unsigned int)u) << 16);
}

static __device__ __forceinline__ bf16x8 ld8(const unsigned short* p) {
  return __builtin_bit_cast(bf16x8, *reinterpret_cast<const short8*>(p));
}

// raw HW exp2 (avoid any libm wrapper)
static __device__ __forceinline__ float exp2_raw(float x) {
  float r; asm("v_exp_f32 %0, %1" : "=v"(r) : "v"(x)); return r;
}
// packed f32x2 -> bf16x2 (T12 recipe; no builtin exists)
static __device__ __forceinline__ unsigned cvtpk(float lo, float hi) {
  unsigned r;
  asm("v_cvt_pk_bf16_f32 %0, %1, %2" : "=v"(r) : "v"(lo), "v"(hi));
  return r;
}

// register-transpose building block: exchange reg-pair bit with lane bit5/bit4
static __device__ __forceinline__ void pl32swap(unsigned& a, unsigned& b) {
  auto r = __builtin_amdgcn_permlane32_swap(a, b, false, false);
  a = r[0]; b = r[1];
}
static __device__ __forceinline__ void pl16swap(unsigned& a, unsigned& b) {
  auto r = __builtin_amdgcn_permlane16_swap(a, b, false, false);
  a = r[0]; b = r[1];
}
// butterfly reduce across lane bit5 / bit4
static __device__ __forceinline__ float red32max(float x) {
  unsigned xi = __builtin_bit_cast(unsigned, x);
  auto r = __builtin_amdgcn_permlane32_swap(xi, xi, false, false);
  return fmaxf(__builtin_bit_cast(float, r[0]), __builtin_bit_cast(float, r[1]));
}
static __device__ __forceinline__ float red16max(float x) {
  unsigned xi = __builtin_bit_cast(unsigned, x);
  auto r = __builtin_amdgcn_permlane16_swap(xi, xi, false, false);
  return fmaxf(__builtin_bit_cast(float, r[0]), __builtin_bit_cast(float, r[1]));
}
static __device__ __forceinline__ float red32sum(float x) {
  unsigned xi = __builtin_bit_cast(unsigned, x);
  auto r = __builtin_amdgcn_permlane32_swap(xi, xi, false, false);
  return __builtin_bit_cast(float, r[0]) + __builtin_bit_cast(float, r[1]);
}
static __device__ __forceinline__ float red16sum(float x) {
  unsigned xi = __builtin_bit_cast(unsigned, x);
  auto r = __builtin_amdgcn_permlane16_swap(xi, xi, false, false);
  return __builtin_bit_cast(float, r[0]) + __builtin_bit_cast(float, r[1]);
}

// ---------------------------------------------------------------- casts ----
__global__ __launch_bounds__(256) void cast_all(
    const float* __restrict__ h, const float* __restrict__ wqkv,
    const float* __restrict__ wo, const float* __restrict__ wgu,
    const float* __restrict__ wd,
    unsigned short* __restrict__ hb, unsigned short* __restrict__ wqkvb,
    unsigned short* __restrict__ wob, unsigned short* __restrict__ wgub,
    unsigned short* __restrict__ wdb) {
  const int n0 = 786432, n1 = 442368, n2 = 147456, n3 = 786432, n4 = 393216;
  const int total = n0 + n1 + n2 + n3 + n4;   // in float4 units
  for (int i = blockIdx.x * blockDim.x + threadIdx.x; i < total;
       i += gridDim.x * blockDim.x) {
    int j = i;
    const float* src; unsigned short* dst;
    if      (j < n0)            { src = h;    dst = hb;    }
    else if ((j -= n0) < n1)    { src = wqkv; dst = wqkvb; }
    else if ((j -= n1) < n2)    { src = wo;   dst = wob;   }
    else if ((j -= n2) < n3)    { src = wgu;  dst = wgub;  }
    else    { j -= n3;            src = wd;   dst = wdb;   }
    float4v v = *reinterpret_cast<const float4v*>(src + 4 * (size_t)j);
    short4v o;
#pragma unroll
    for (int e = 0; e < 4; ++e) o[e] = (short)f2bf(v[e]);
    *reinterpret_cast<short4v*>(dst + 4 * (size_t)j) = o;
  }
}

// ----------------------------------------------------------------- GEMM ----
// C[m][n] = sum_k A[m][k] * W[n][k].  BM=128 x BN block tile, BK=32,
// 4 waves, global_load_lds staging. BN=128: waves 2x2 (64x64 each);
// BN=64: waves 4x1 (32x64 each) -> 2x the blocks for small-N GEMMs.
template <int BN, bool BF16OUT>
__global__ __launch_bounds__(256) void gemm_lds(
    const unsigned short* __restrict__ A, const unsigned short* __restrict__ W,
    void* __restrict__ Cout, int Mm, int Nn, int Kk) {
  constexpr int MR = (BN == 128) ? 4 : 2;   // 16-row m-frags per wave
  __shared__ unsigned short Alds[4096];     // [128][32]
  __shared__ unsigned short Blds[BN * 32];
  const int t = threadIdx.x;
  const int lane = t & 63, w = t >> 6;
  const int lr = lane & 15, lg = lane >> 4;
  const int row0 = blockIdx.y * 128, col0 = blockIdx.x * BN;
  const int wrb = (BN == 128) ? (w >> 1) * 64 : w * 32;  // wave row base
  const int wcb = (BN == 128) ? (w & 1) * 64 : 0;        // wave col base

  const unsigned short* ga = A + (size_t)(row0 + (t >> 2)) * Kk + (t & 3) * 8;
  const unsigned short* gb = W + (size_t)(col0 + (t >> 2)) * Kk + (t & 3) * 8;
  const size_t g64 = (size_t)64 * Kk;
  unsigned short* la0 = Alds + w * 512;   // wave-uniform LDS base
  unsigned short* lb0 = Blds + w * 512;
  const unsigned short* ra = Alds + (wrb + lr) * 32 + lg * 8;
  const unsigned short* rb = Blds + (wcb + lr) * 32 + lg * 8;

  f32x4 acc[MR][4] = {};
  for (int k0 = 0; k0 < Kk; k0 += 32) {
    __builtin_amdgcn_global_load_lds((const unsigned int*)(ga + k0),
                                     (unsigned int*)la0, 16, 0, 0);
    __builtin_amdgcn_global_load_lds((const unsigned int*)(ga + k0 + g64),
                                     (unsigned int*)(la0 + 2048), 16, 0, 0);
    __builtin_amdgcn_global_load_lds((const unsigned int*)(gb + k0),
                                     (unsigned int*)lb0, 16, 0, 0);
    if constexpr (BN == 128)
      __builtin_amdgcn_global_load_lds((const unsigned int*)(gb + k0 + g64),
                                       (unsigned int*)(lb0 + 2048), 16, 0, 0);
    __syncthreads();
    bf16x8 af[MR], bfr[4];
#pragma unroll
    for (int m = 0; m < MR; ++m) af[m] = ld8(ra + m * 512);
#pragma unroll
    for (int n = 0; n < 4; ++n) bfr[n] = ld8(rb + n * 512);
    __builtin_amdgcn_s_setprio(1);
#pragma unroll
    for (int m = 0; m < MR; ++m)
#pragma unroll
      for (int n = 0; n < 4; ++n)
        acc[m][n] = __builtin_amdgcn_mfma_f32_16x16x32_bf16(af[m], bfr[n],
                                                            acc[m][n], 0, 0, 0);
    __builtin_amdgcn_s_setprio(0);
    __syncthreads();
  }
#pragma unroll
  for (int m = 0; m < MR; ++m)
#pragma unroll
    for (int j = 0; j < 4; ++j) {
      const size_t roff = (size_t)(row0 + wrb + m * 16 + lg * 4 + j) * Nn +
                          col0 + wcb + lr;
      if constexpr (BF16OUT) {
        unsigned short* cr = (unsigned short*)Cout + roff;
#pragma unroll
        for (int n = 0; n < 4; ++n) cr[n * 16] = f2bf(acc[m][n][j]);
      } else {
        float* cr = (float*)Cout + roff;
#pragma unroll
        for (int n = 0; n < 4; ++n) cr[n * 16] = acc[m][n][j];
      }
    }
}

// ----------------------------------------------------------------- RoPE ----
// q,k rows of qkv bf16 -> rope -> fragment-order tiles:
//   tile[bh][t=s/16][dh=d/32][lane=lg*16+lr][j]  (lr=s%16, lg=(d%32)/8, j=d%8)
__global__ __launch_bounds__(256) void rope_qk(
    const unsigned short* __restrict__ qkv, const float* __restrict__ cosT,
    const float* __restrict__ sinT, unsigned short* __restrict__ qtile,
    unsigned short* __restrict__ ktile) {
  const int row = blockIdx.x * 4 + (threadIdx.x >> 6);   // 0 .. B*S*24-1
  const int d = threadIdx.x & 63;
  const int hh = row % 24;
  const int bs = row / 24;
  const int s = bs & (SEQ - 1);
  const int b = bs >> 11;
  float v = bf2f(qkv[(size_t)bs * QKV_N + hh * 64 + d]);
  float partner = __shfl_xor(v, 32, 64);
  float rot = (d < 32) ? -partner : partner;
  v = v * cosT[s * 64 + d] + rot * sinT[s * 64 + d];
  const int t = s >> 4, lr = s & 15;
  const int dh = d >> 5, lg = (d & 31) >> 3, j = d & 7;
  if (hh < 12) {
    const int bh = b * HEADS + hh;
    qtile[((size_t)(bh * 128 + t) * 2 + dh) * 512 + (lg * 16 + lr) * 8 + j] =
        f2bf(v * QSCALE);
  } else {
    const int bh = b * HEADS + (hh - 12);
    ktile[((size_t)(bh * 128 + t) * 2 + dh) * 512 + (lg * 16 + lr) * 8 + j] =
        f2bf(v);
  }
}

// V transpose through padded LDS -> fragment-order tiles:
//   vtile[bh][k32][d0][lane][j] holds V[k32*32+lg*8+j][d0*16+lr]
__global__ __launch_bounds__(256) void v_trans(
    const unsigned short* __restrict__ qkv, unsigned short* __restrict__ vT) {
  __shared__ unsigned short tile[64][66];
  const int bh = blockIdx.x;               // b*HEADS+h
  const int s0 = blockIdx.y * 64;
  const int b = bh / HEADS, h = bh % HEADS;
  const unsigned short* src = qkv + ((size_t)(b * SEQ + s0)) * QKV_N + (24 + h) * 64;
  const int d = threadIdx.x & 63, sg = threadIdx.x >> 6;
#pragma unroll
  for (int i = 0; i < 16; ++i) {
    int s = sg * 16 + i;
    tile[s][d] = src[(size_t)s * QKV_N + d];
  }
  __syncthreads();
  const int lane = threadIdx.x & 63, wid = threadIdx.x >> 6;
  const int lr = lane & 15, lg = lane >> 4;
  unsigned short* dst = vT + ((size_t)bh * 64 + (s0 >> 5)) * 4 * 512;
#pragma unroll
  for (int tt = 0; tt < 2; ++tt) {
    const int ti = wid * 2 + tt;
    const int kt = ti >> 2, d0 = (ti & 3) * 16;
    short8 o;
#pragma unroll
    for (int j = 0; j < 8; ++j)
      o[j] = (short)tile[kt * 32 + lg * 8 + j][d0 + lr];
    *reinterpret_cast<short8*>(dst + ((size_t)kt * 4 + (ti & 3)) * 512 +
                               lane * 8) = o;
  }
}

// ------------------------------------------------------------ attention ----
// KV-split flash attention, 64 keys per iteration, raw exp2/cvt_pk,
// deferred cross-lane l-reduction. One wave per (16 q-rows, 512 keys).
__global__ __launch_bounds__(256) void attn_fused(
    const unsigned short* __restrict__ qtile, const unsigned short* __restrict__ ktile,
    const unsigned short* __restrict__ vtile, unsigned short* __restrict__ ctxp,
    float2* __restrict__ ml) {
  const int lane = threadIdx.x & 63, wid = threadIdx.x >> 6;
  const int tid = blockIdx.x * 4 + wid;        // 0 .. 12287
  const int sp = tid & 3;
  const int qt = (tid >> 2) & 127;
  const int bh = tid >> 9;
  const int lr = lane & 15, lg = lane >> 4;

  const unsigned short* qp =
      qtile + ((size_t)(bh * 128 + qt) * 2) * 512 + lane * 8;
  bf16x8 qf0 = ld8(qp);
  bf16x8 qf1 = ld8(qp + 512);
  const unsigned short* kb = ktile + (size_t)bh * 128 * 2 * 512 + lane * 8;
  const unsigned short* vb = vtile + (size_t)bh * 64 * 4 * 512 + lane * 8;

  f32x4 acc0 = {0,0,0,0}, acc1 = {0,0,0,0}, acc2 = {0,0,0,0}, acc3 = {0,0,0,0};
  float m = -1e30f, l_lane = 0.f;

  for (int k0 = sp * KCHUNK; k0 < sp * KCHUNK + KCHUNK; k0 += 64) {
    const unsigned short* kp = kb + (size_t)(k0 >> 4) * 1024;
    f32x4 st0 = {0,0,0,0}, st1 = {0,0,0,0}, st2 = {0,0,0,0}, st3 = {0,0,0,0};
    __builtin_amdgcn_s_setprio(1);
    st0 = __builtin_amdgcn_mfma_f32_16x16x32_bf16(ld8(kp),        qf0, st0, 0,0,0);
    st0 = __builtin_amdgcn_mfma_f32_16x16x32_bf16(ld8(kp + 512),  qf1, st0, 0,0,0);
    st1 = __builtin_amdgcn_mfma_f32_16x16x32_bf16(ld8(kp + 1024), qf0, st1, 0,0,0);
    st1 = __builtin_amdgcn_mfma_f32_16x16x32_bf16(ld8(kp + 1536), qf1, st1, 0,0,0);
    st2 = __builtin_amdgcn_mfma_f32_16x16x32_bf16(ld8(kp + 2048), qf0, st2, 0,0,0);
    st2 = __builtin_amdgcn_mfma_f32_16x16x32_bf16(ld8(kp + 2560), qf1, st2, 0,0,0);
    st3 = __builtin_amdgcn_mfma_f32_16x16x32_bf16(ld8(kp + 3072), qf0, st3, 0,0,0);
    st3 = __builtin_amdgcn_mfma_f32_16x16x32_bf16(ld8(kp + 3584), qf1, st3, 0,0,0);
    __builtin_amdgcn_s_setprio(0);

    // per-q-column max over 64 keys
    float tmax = fmaxf(
        fmaxf(fmaxf(fmaxf(st0[0], st0[1]), fmaxf(st0[2], st0[3])),
              fmaxf(fmaxf(st1[0], st1[1]), fmaxf(st1[2], st1[3]))),
        fmaxf(fmaxf(fmaxf(st2[0], st2[1]), fmaxf(st2[2], st2[3])),
              fmaxf(fmaxf(st3[0], st3[1]), fmaxf(st3[2], st3[3]))));
    tmax = red16max(red32max(tmax));

    if (tmax > m + 11.0f) {   // defer-max: rescale only on real growth
      float fac = exp2_raw(m - tmax);
      m = tmax;
      l_lane *= fac;
      acc0 *= fac; acc1 *= fac; acc2 *= fac; acc3 *= fac;
    }

    float p[16];
#pragma unroll
    for (int r = 0; r < 4; ++r) {
      p[r]      = exp2_raw(st0[r] - m);
      p[4 + r]  = exp2_raw(st1[r] - m);
      p[8 + r]  = exp2_raw(st2[r] - m);
      p[12 + r] = exp2_raw(st3[r] - m);
    }
    l_lane += (((p[0] + p[1]) + (p[2] + p[3])) +
               ((p[4] + p[5]) + (p[6] + p[7]))) +
              (((p[8] + p[9]) + (p[10] + p[11])) +
               ((p[12] + p[13]) + (p[14] + p[15])));

    // register transpose into PV B-fragments (one per 32-key half)
    unsigned c0 = cvtpk(p[0], p[1]),   c1 = cvtpk(p[2], p[3]);
    unsigned c2 = cvtpk(p[4], p[5]),   c3 = cvtpk(p[6], p[7]);
    unsigned c4 = cvtpk(p[8], p[9]),   c5 = cvtpk(p[10], p[11]);
    unsigned c6 = cvtpk(p[12], p[13]), c7 = cvtpk(p[14], p[15]);
    pl32swap(c0, c2); pl32swap(c1, c3); pl16swap(c0, c2); pl16swap(c1, c3);
    pl32swap(c4, c6); pl32swap(c5, c7); pl16swap(c4, c6); pl16swap(c5, c7);
    u32x4 pw0 = {c0, c1, c2, c3};
    u32x4 pw1 = {c4, c5, c6, c7};
    bf16x8 pf0 = __builtin_bit_cast(bf16x8, pw0);
    bf16x8 pf1 = __builtin_bit_cast(bf16x8, pw1);

    const unsigned short* vp = vb + (size_t)(k0 >> 5) * 2048;
    __builtin_amdgcn_s_setprio(1);
    acc0 = __builtin_amdgcn_mfma_f32_16x16x32_bf16(ld8(vp),        pf0, acc0, 0,0,0);
    acc1 = __builtin_amdgcn_mfma_f32_16x16x32_bf16(ld8(vp + 512),  pf0, acc1, 0,0,0);
    acc2 = __builtin_amdgcn_mfma_f32_16x16x32_bf16(ld8(vp + 1024), pf0, acc2, 0,0,0);
    acc3 = __builtin_amdgcn_mfma_f32_16x16x32_bf16(ld8(vp + 1536), pf0, acc3, 0,0,0);
    acc0 = __builtin_amdgcn_mfma_f32_16x16x32_bf16(ld8(vp + 2048), pf1, acc0, 0,0,0);
    acc1 = __builtin_amdgcn_mfma_f32_16x16x32_bf16(ld8(vp + 2560), pf1, acc1, 0,0,0);
    acc2 = __builtin_amdgcn_mfma_f32_16x16x32_bf16(ld8(vp + 3072), pf1, acc2, 0,0,0);
    acc3 = __builtin_amdgcn_mfma_f32_16x16x32_bf16(ld8(vp + 3584), pf1, acc3, 0,0,0);
    __builtin_amdgcn_s_setprio(0);
  }

  const float l = red16sum(red32sum(l_lane));

  // unnormalized bf16 partial + (m,l)
  unsigned short* pp = ctxp +
      (((size_t)(sp * BH + bh)) * SEQ + qt * 16 + lr) * DH + 4 * lg;
  short4v o0, o1, o2, o3;
#pragma unroll
  for (int r = 0; r < 4; ++r) {
    o0[r] = (short)f2bf(acc0[r]);
    o1[r] = (short)f2bf(acc1[r]);
    o2[r] = (short)f2bf(acc2[r]);
    o3[r] = (short)f2bf(acc3[r]);
  }
  *reinterpret_cast<short4v*>(pp)      = o0;
  *reinterpret_cast<short4v*>(pp + 16) = o1;
  *reinterpret_cast<short4v*>(pp + 32) = o2;
  *reinterpret_cast<short4v*>(pp + 48) = o3;
  if (lane < 16) {
    float2 v; v.x = m; v.y = l;
    ml[(size_t)sp * (BH * SEQ) + bh * SEQ + qt * 16 + lr] = v;
  }
}

// combine the NSPLIT partials -> ctx bf16 (B*S, 768)
__global__ __launch_bounds__(256) void attn_combine(
    const unsigned short* __restrict__ ctxp, const float2* __restrict__ ml,
    unsigned short* __restrict__ ctx) {
  const int idx = blockIdx.x * 256 + threadIdx.x;  // over BH*SEQ*DH
  const int d = idx & 63;
  const int row = idx >> 6;                        // bh*SEQ + s
  float m0 = ml[row].x,                 l0 = ml[row].y;
  float m1 = ml[row + BH*SEQ].x,        l1 = ml[row + BH*SEQ].y;
  float m2 = ml[row + 2*BH*SEQ].x,      l2 = ml[row + 2*BH*SEQ].y;
  float m3 = ml[row + 3*BH*SEQ].x,      l3 = ml[row + 3*BH*SEQ].y;
  float M = fmaxf(fmaxf(m0, m1), fmaxf(m2, m3));
  float w0 = exp2_raw(m0 - M), w1 = exp2_raw(m1 - M);
  float w2 = exp2_raw(m2 - M), w3 = exp2_raw(m3 - M);
  float den = w0 * l0 + w1 * l1 + w2 * l2 + w3 * l3;
  const size_t pstride = (size_t)BH * SEQ * DH;
  float num = w0 * bf2f(ctxp[(size_t)row * DH + d]) +
              w1 * bf2f(ctxp[(size_t)row * DH + d + pstride]) +
              w2 * bf2f(ctxp[(size_t)row * DH + d + 2 * pstride]) +
              w3 * bf2f(ctxp[(size_t)row * DH + d + 3 * pstride]);
  const int bh = row >> 11, s = row & (SEQ - 1);
  const int b = bh / HEADS, h = bh % HEADS;
  ctx[((size_t)(b * SEQ + s)) * CDIM + h * DH + d] = f2bf(num / den);
}

// ---------------------------------------------------------- add+rmsnorm ----
__global__ __launch_bounds__(256) void add_rmsnorm(
    const float* __restrict__ a, const float* __restrict__ b,
    float* __restrict__ outf, unsigned short* __restrict__ outb) {
  const int row = blockIdx.x;
  const int tid = threadIdx.x;
  const float* ap = a + (size_t)row * CDIM;
  const float* bp = b + (size_t)row * CDIM;
  float v0 = ap[tid]       + bp[tid];
  float v1 = ap[tid + 256] + bp[tid + 256];
  float v2 = ap[tid + 512] + bp[tid + 512];
  float ss = v0 * v0 + v1 * v1 + v2 * v2;
#pragma unroll
  for (int off = 32; off > 0; off >>= 1) ss += __shfl_xor(ss, off, 64);
  __shared__ float red[4];
  if ((tid & 63) == 0) red[tid >> 6] = ss;
  __syncthreads();
  float tot = red[0] + red[1] + red[2] + red[3];
  float r = rsqrtf(tot * (1.f / 768.f) + 1e-5f);
  float* of = outf + (size_t)row * CDIM;
  of[tid]       = v0 * r;
  of[tid + 256] = v1 * r;
  of[tid + 512] = v2 * r;
  if (outb) {
    unsigned short* ob = outb + (size_t)row * CDIM;
    ob[tid]       = f2bf(v0 * r);
    ob[tid + 256] = f2bf(v1 * r);
    ob[tid + 512] = f2bf(v2 * r);
  }
}

// ------------------------------------------------------------- silu*mul ----
__global__ __launch_bounds__(256) void silu_mul(
    const unsigned short* __restrict__ gu, unsigned short* __restrict__ hb) {
  const int i = blockIdx.x * 256 + threadIdx.x;  // < MROWS*INTER
  const int s = i >> 11, c = i & (INTER - 1);
  float g = bf2f(gu[(size_t)s * GU_N + c]);
  float u = bf2f(gu[(size_t)s * GU_N + INTER + c]);
  float sig = 1.f / (1.f + __expf(-g));
  hb[i] = f2bf(g * sig * u);
}

// ----------------------------------------------------------------- host ----
extern "C" void kernel_launch(void* const* d_in, const int* in_sizes, int n_in,
                              void* d_out, int out_size, void* d_ws, size_t ws_size,
                              hipStream_t stream) {
  const float* hidden = (const float*)d_in[0];
  const float* cosT   = (const float*)d_in[1];
  const float* sinT   = (const float*)d_in[2];
  const float* wqkv   = (const float*)d_in[3];
  const float* wo     = (const float*)d_in[4];
  const float* wgu    = (const float*)d_in[5];
  const float* wd     = (const float*)d_in[6];
  float* out = (float*)d_out;

  char* wsp = (char*)d_ws;
  size_t off = 0;
  auto alloc = [&](size_t bytes) { void* p = wsp + off; off += bytes; return p; };

  // persistent
  unsigned short* wqkvb = (unsigned short*)alloc(2ull * 1769472);
  unsigned short* wob   = (unsigned short*)alloc(2ull * 589824);
  unsigned short* wgub  = (unsigned short*)alloc(2ull * 3145728);
  unsigned short* wdb   = (unsigned short*)alloc(2ull * 1572864);
  unsigned short* hb    = (unsigned short*)alloc(2ull * 3145728);
  float*          x     = (float*)alloc(4ull * 3145728);
  unsigned short* xb    = (unsigned short*)alloc(2ull * 3145728);
  const size_t roff = off;

  // phase A (through attention)
  unsigned short* qkvb = (unsigned short*)alloc(2ull * MROWS * QKV_N);
  unsigned short* qT   = (unsigned short*)alloc(2ull * MROWS * CDIM);
  unsigned short* kT   = (unsigned short*)alloc(2ull * MROWS * CDIM);
  unsigned short* vTb  = (unsigned short*)alloc(2ull * MROWS * CDIM);
  unsigned short* ctx  = (unsigned short*)alloc(2ull * MROWS * CDIM);
  float*          attn = (float*)alloc(4ull * MROWS * CDIM);
  unsigned short* ctxp = (unsigned short*)alloc(2ull * NSPLIT * BH * SEQ * DH);
  float2*         ml   = (float2*)alloc(8ull * NSPLIT * BH * SEQ);

  // phase B (MLP) aliases phase A
  off = roff;
  unsigned short* gub  = (unsigned short*)alloc(2ull * MROWS * GU_N);
  unsigned short* hmid = (unsigned short*)alloc(2ull * MROWS * INTER);
  float*          mlp  = (float*)alloc(4ull * MROWS * CDIM);
  (void)ws_size; (void)in_sizes; (void)n_in; (void)out_size;

  // 1. casts
  cast_all<<<2048, 256, 0, stream>>>(hidden, wqkv, wo, wgu, wd,
                                     hb, wqkvb, wob, wgub, wdb);
  // 2. qkv = hidden @ w_qkv^T (bf16 out)
  gemm_lds<128, true><<<dim3(QKV_N / 128, MROWS / 128), 256, 0, stream>>>(
      hb, wqkvb, qkvb, MROWS, QKV_N, CDIM);
  // 3. rope (q,k) + v transpose into fragment-order tiles
  rope_qk<<<(MROWS * 24) / 4, 256, 0, stream>>>(qkvb, cosT, sinT, qT, kT);
  v_trans<<<dim3(BH, SEQ / 64), 256, 0, stream>>>(qkvb, vTb);
  // 4. attention (KV-split) + combine
  attn_fused<<<(BH * (SEQ / 16) * NSPLIT) / 4, 256, 0, stream>>>(
      qT, kT, vTb, ctxp, ml);
  attn_combine<<<(BH * SEQ * DH) / 256, 256, 0, stream>>>(ctxp, ml, ctx);
  // 5. attn_out = ctx @ w_o^T  (BN=64 -> 384 blocks)
  gemm_lds<64, false><<<dim3(CDIM / 64, MROWS / 128), 256, 0, stream>>>(
      ctx, wob, attn, MROWS, CDIM, CDIM);
  // 6. x = rmsnorm(hidden + attn)
  add_rmsnorm<<<MROWS, 256, 0, stream>>>(hidden, attn, x, xb);
  // 7. gu = x @ w_gate_up^T (bf16 out)
  gemm_lds<128, true><<<dim3(GU_N / 128, MROWS / 128), 256, 0, stream>>>(
      xb, wgub, gub, MROWS, GU_N, CDIM);
  // 8. h = silu(gate)*up
  silu_mul<<<(MROWS * INTER) / 256, 256, 0, stream>>>(gub, hmid);
  // 9. mlp = h @ w_down^T  (BN=64 -> 384 blocks)
  gemm_lds<64, false><<<dim3(CDIM / 64, MROWS / 128), 256, 0, stream>>>(
      hmid, wdb, mlp, MROWS, CDIM, INTER);
  // 10. out = rmsnorm(x + mlp)
  add_rmsnorm<<<MROWS, 256, 0, stream>>>(x, mlp, out, nullptr);
}

// Round 10
// 326.300 us; speedup vs baseline: 1.4141x; 1.0709x over previous
//
#include <hip/hip_runtime.h>

// EBT transformer block on MI355X. All GEMMs via mfma_f32_16x16x32_bf16
// (fp32 accumulate) with global_load_lds staging; flash attention with
// KV-split=4, fragment-order tiled Q/K/V, 2 q-tiles per wave (K/V frag
// reuse), swapped QK^T, permlane softmax, raw v_exp_f32 / v_cvt_pk_bf16_f32.

typedef __attribute__((ext_vector_type(8))) __bf16 bf16x8;
typedef __attribute__((ext_vector_type(8))) short short8;
typedef __attribute__((ext_vector_type(4))) short short4v;
typedef __attribute__((ext_vector_type(4))) float f32x4;
typedef __attribute__((ext_vector_type(4))) float float4v;
typedef __attribute__((ext_vector_type(4))) unsigned int u32x4;

#define CDIM   768
#define HEADS  12
#define DH     64
#define SEQ    2048
#define BATCH  2
#define MROWS  4096      // B*S
#define QKV_N  2304      // 3*H*D
#define INTER  2048
#define GU_N   4096      // 2*INTER
#define NSPLIT 4
#define KCHUNK (SEQ / NSPLIT)   // 512
#define BH     (BATCH * HEADS)  // 24

// log2(e)/8 folded into Q so scores are already in exp2 domain.
#define QSCALE 0.18033688011112043f

static __device__ __forceinline__ unsigned short f2bf(float f) {
  unsigned int u = __builtin_bit_cast(unsigned int, f);
  u += 0x7fffu + ((u >> 16) & 1u);
  return (unsigned short)(u >> 16);
}
static __device__ __forceinline__ float bf2f(unsigned short u) {
  return __builtin_bit_cast(float, ((unsigned int)u) << 16);
}

static __device__ __forceinline__ bf16x8 ld8(const unsigned short* p) {
  return __builtin_bit_cast(bf16x8, *reinterpret_cast<const short8*>(p));
}

// raw HW exp2 (avoid any libm wrapper)
static __device__ __forceinline__ float exp2_raw(float x) {
  float r; asm("v_exp_f32 %0, %1" : "=v"(r) : "v"(x)); return r;
}
// packed f32x2 -> bf16x2 (T12 recipe; no builtin exists)
static __device__ __forceinline__ unsigned cvtpk(float lo, float hi) {
  unsigned r;
  asm("v_cvt_pk_bf16_f32 %0, %1, %2" : "=v"(r) : "v"(lo), "v"(hi));
  return r;
}

// register-transpose building block: exchange reg-pair bit with lane bit5/bit4
static __device__ __forceinline__ void pl32swap(unsigned& a, unsigned& b) {
  auto r = __builtin_amdgcn_permlane32_swap(a, b, false, false);
  a = r[0]; b = r[1];
}
static __device__ __forceinline__ void pl16swap(unsigned& a, unsigned& b) {
  auto r = __builtin_amdgcn_permlane16_swap(a, b, false, false);
  a = r[0]; b = r[1];
}
// butterfly reduce across lane bit5 / bit4
static __device__ __forceinline__ float red32max(float x) {
  unsigned xi = __builtin_bit_cast(unsigned, x);
  auto r = __builtin_amdgcn_permlane32_swap(xi, xi, false, false);
  return fmaxf(__builtin_bit_cast(float, r[0]), __builtin_bit_cast(float, r[1]));
}
static __device__ __forceinline__ float red16max(float x) {
  unsigned xi = __builtin_bit_cast(unsigned, x);
  auto r = __builtin_amdgcn_permlane16_swap(xi, xi, false, false);
  return fmaxf(__builtin_bit_cast(float, r[0]), __builtin_bit_cast(float, r[1]));
}
static __device__ __forceinline__ float red32sum(float x) {
  unsigned xi = __builtin_bit_cast(unsigned, x);
  auto r = __builtin_amdgcn_permlane32_swap(xi, xi, false, false);
  return __builtin_bit_cast(float, r[0]) + __builtin_bit_cast(float, r[1]);
}
static __device__ __forceinline__ float red16sum(float x) {
  unsigned xi = __builtin_bit_cast(unsigned, x);
  auto r = __builtin_amdgcn_permlane16_swap(xi, xi, false, false);
  return __builtin_bit_cast(float, r[0]) + __builtin_bit_cast(float, r[1]);
}

// ---------------------------------------------------------------- casts ----
__global__ __launch_bounds__(256) void cast_all(
    const float* __restrict__ h, const float* __restrict__ wqkv,
    const float* __restrict__ wo, const float* __restrict__ wgu,
    const float* __restrict__ wd,
    unsigned short* __restrict__ hb, unsigned short* __restrict__ wqkvb,
    unsigned short* __restrict__ wob, unsigned short* __restrict__ wgub,
    unsigned short* __restrict__ wdb) {
  const int n0 = 786432, n1 = 442368, n2 = 147456, n3 = 786432, n4 = 393216;
  const int total = n0 + n1 + n2 + n3 + n4;   // in float4 units
  for (int i = blockIdx.x * blockDim.x + threadIdx.x; i < total;
       i += gridDim.x * blockDim.x) {
    int j = i;
    const float* src; unsigned short* dst;
    if      (j < n0)            { src = h;    dst = hb;    }
    else if ((j -= n0) < n1)    { src = wqkv; dst = wqkvb; }
    else if ((j -= n1) < n2)    { src = wo;   dst = wob;   }
    else if ((j -= n2) < n3)    { src = wgu;  dst = wgub;  }
    else    { j -= n3;            src = wd;   dst = wdb;   }
    float4v v = *reinterpret_cast<const float4v*>(src + 4 * (size_t)j);
    short4v o;
#pragma unroll
    for (int e = 0; e < 4; ++e) o[e] = (short)f2bf(v[e]);
    *reinterpret_cast<short4v*>(dst + 4 * (size_t)j) = o;
  }
}

// ----------------------------------------------------------------- GEMM ----
// C[m][n] = sum_k A[m][k] * W[n][k].  BM=128 x BN block tile, BK=32,
// 4 waves, global_load_lds staging. BN=128: waves 2x2; BN=64: waves 4x1.
template <int BN, bool BF16OUT>
__global__ __launch_bounds__(256) void gemm_lds(
    const unsigned short* __restrict__ A, const unsigned short* __restrict__ W,
    void* __restrict__ Cout, int Mm, int Nn, int Kk) {
  constexpr int MR = (BN == 128) ? 4 : 2;   // 16-row m-frags per wave
  __shared__ unsigned short Alds[4096];     // [128][32]
  __shared__ unsigned short Blds[BN * 32];
  const int t = threadIdx.x;
  const int lane = t & 63, w = t >> 6;
  const int lr = lane & 15, lg = lane >> 4;
  const int row0 = blockIdx.y * 128, col0 = blockIdx.x * BN;
  const int wrb = (BN == 128) ? (w >> 1) * 64 : w * 32;  // wave row base
  const int wcb = (BN == 128) ? (w & 1) * 64 : 0;        // wave col base

  const unsigned short* ga = A + (size_t)(row0 + (t >> 2)) * Kk + (t & 3) * 8;
  const unsigned short* gb = W + (size_t)(col0 + (t >> 2)) * Kk + (t & 3) * 8;
  const size_t g64 = (size_t)64 * Kk;
  unsigned short* la0 = Alds + w * 512;   // wave-uniform LDS base
  unsigned short* lb0 = Blds + w * 512;
  const unsigned short* ra = Alds + (wrb + lr) * 32 + lg * 8;
  const unsigned short* rb = Blds + (wcb + lr) * 32 + lg * 8;

  f32x4 acc[MR][4] = {};
  for (int k0 = 0; k0 < Kk; k0 += 32) {
    __builtin_amdgcn_global_load_lds((const unsigned int*)(ga + k0),
                                     (unsigned int*)la0, 16, 0, 0);
    __builtin_amdgcn_global_load_lds((const unsigned int*)(ga + k0 + g64),
                                     (unsigned int*)(la0 + 2048), 16, 0, 0);
    __builtin_amdgcn_global_load_lds((const unsigned int*)(gb + k0),
                                     (unsigned int*)lb0, 16, 0, 0);
    if constexpr (BN == 128)
      __builtin_amdgcn_global_load_lds((const unsigned int*)(gb + k0 + g64),
                                       (unsigned int*)(lb0 + 2048), 16, 0, 0);
    __syncthreads();
    bf16x8 af[MR], bfr[4];
#pragma unroll
    for (int m = 0; m < MR; ++m) af[m] = ld8(ra + m * 512);
#pragma unroll
    for (int n = 0; n < 4; ++n) bfr[n] = ld8(rb + n * 512);
    __builtin_amdgcn_s_setprio(1);
#pragma unroll
    for (int m = 0; m < MR; ++m)
#pragma unroll
      for (int n = 0; n < 4; ++n)
        acc[m][n] = __builtin_amdgcn_mfma_f32_16x16x32_bf16(af[m], bfr[n],
                                                            acc[m][n], 0, 0, 0);
    __builtin_amdgcn_s_setprio(0);
    __syncthreads();
  }
#pragma unroll
  for (int m = 0; m < MR; ++m)
#pragma unroll
    for (int j = 0; j < 4; ++j) {
      const size_t roff = (size_t)(row0 + wrb + m * 16 + lg * 4 + j) * Nn +
                          col0 + wcb + lr;
      if constexpr (BF16OUT) {
        unsigned short* cr = (unsigned short*)Cout + roff;
#pragma unroll
        for (int n = 0; n < 4; ++n) cr[n * 16] = f2bf(acc[m][n][j]);
      } else {
        float* cr = (float*)Cout + roff;
#pragma unroll
        for (int n = 0; n < 4; ++n) cr[n * 16] = acc[m][n][j];
      }
    }
}

// ----------------------------------------------------------------- RoPE ----
// q,k rows of qkv bf16 -> rope -> fragment-order tiles:
//   tile[bh][t=s/16][dh=d/32][lane=lg*16+lr][j]  (lr=s%16, lg=(d%32)/8, j=d%8)
__global__ __launch_bounds__(256) void rope_qk(
    const unsigned short* __restrict__ qkv, const float* __restrict__ cosT,
    const float* __restrict__ sinT, unsigned short* __restrict__ qtile,
    unsigned short* __restrict__ ktile) {
  const int row = blockIdx.x * 4 + (threadIdx.x >> 6);   // 0 .. B*S*24-1
  const int d = threadIdx.x & 63;
  const int hh = row % 24;
  const int bs = row / 24;
  const int s = bs & (SEQ - 1);
  const int b = bs >> 11;
  float v = bf2f(qkv[(size_t)bs * QKV_N + hh * 64 + d]);
  float partner = __shfl_xor(v, 32, 64);
  float rot = (d < 32) ? -partner : partner;
  v = v * cosT[s * 64 + d] + rot * sinT[s * 64 + d];
  const int t = s >> 4, lr = s & 15;
  const int dh = d >> 5, lg = (d & 31) >> 3, j = d & 7;
  if (hh < 12) {
    const int bh = b * HEADS + hh;
    qtile[((size_t)(bh * 128 + t) * 2 + dh) * 512 + (lg * 16 + lr) * 8 + j] =
        f2bf(v * QSCALE);
  } else {
    const int bh = b * HEADS + (hh - 12);
    ktile[((size_t)(bh * 128 + t) * 2 + dh) * 512 + (lg * 16 + lr) * 8 + j] =
        f2bf(v);
  }
}

// V transpose through padded LDS -> fragment-order tiles:
//   vtile[bh][k32][d0][lane][j] holds V[k32*32+lg*8+j][d0*16+lr]
__global__ __launch_bounds__(256) void v_trans(
    const unsigned short* __restrict__ qkv, unsigned short* __restrict__ vT) {
  __shared__ unsigned short tile[64][66];
  const int bh = blockIdx.x;               // b*HEADS+h
  const int s0 = blockIdx.y * 64;
  const int b = bh / HEADS, h = bh % HEADS;
  const unsigned short* src = qkv + ((size_t)(b * SEQ + s0)) * QKV_N + (24 + h) * 64;
  const int d = threadIdx.x & 63, sg = threadIdx.x >> 6;
#pragma unroll
  for (int i = 0; i < 16; ++i) {
    int s = sg * 16 + i;
    tile[s][d] = src[(size_t)s * QKV_N + d];
  }
  __syncthreads();
  const int lane = threadIdx.x & 63, wid = threadIdx.x >> 6;
  const int lr = lane & 15, lg = lane >> 4;
  unsigned short* dst = vT + ((size_t)bh * 64 + (s0 >> 5)) * 4 * 512;
#pragma unroll
  for (int tt = 0; tt < 2; ++tt) {
    const int ti = wid * 2 + tt;
    const int kt = ti >> 2, d0 = (ti & 3) * 16;
    short8 o;
#pragma unroll
    for (int j = 0; j < 8; ++j)
      o[j] = (short)tile[kt * 32 + lg * 8 + j][d0 + lr];
    *reinterpret_cast<short8*>(dst + ((size_t)kt * 4 + (ti & 3)) * 512 +
                               lane * 8) = o;
  }
}

// ------------------------------------------------------------ attention ----
// KV-split flash attention, 2 q-tiles (32 q-rows) per wave sharing K/V
// fragments, 64 keys per iteration. One wave per (32 q-rows, 512 keys).
__global__ __launch_bounds__(256) void attn_fused(
    const unsigned short* __restrict__ qtile, const unsigned short* __restrict__ ktile,
    const unsigned short* __restrict__ vtile, unsigned short* __restrict__ ctxp,
    float2* __restrict__ ml) {
  const int lane = threadIdx.x & 63, wid = threadIdx.x >> 6;
  const int tid = blockIdx.x * 4 + wid;        // 0 .. 6143
  const int sp = tid & 3;
  const int qtp = (tid >> 2) & 63;             // 32-row q group
  const int bh = tid >> 8;
  const int lr = lane & 15, lg = lane >> 4;
  const int qt0 = qtp * 2, qt1 = qt0 + 1;

  const unsigned short* qp =
      qtile + ((size_t)(bh * 128 + qt0) * 2) * 512 + lane * 8;
  bf16x8 qA0 = ld8(qp);
  bf16x8 qA1 = ld8(qp + 512);
  bf16x8 qB0 = ld8(qp + 1024);
  bf16x8 qB1 = ld8(qp + 1536);
  const unsigned short* kb = ktile + (size_t)bh * 128 * 2 * 512 + lane * 8;
  const unsigned short* vb = vtile + (size_t)bh * 64 * 4 * 512 + lane * 8;

  f32x4 aA0 = {0,0,0,0}, aA1 = {0,0,0,0}, aA2 = {0,0,0,0}, aA3 = {0,0,0,0};
  f32x4 aB0 = {0,0,0,0}, aB1 = {0,0,0,0}, aB2 = {0,0,0,0}, aB3 = {0,0,0,0};
  float mA = -1e30f, mB = -1e30f, lA = 0.f, lB = 0.f;

  for (int k0 = sp * KCHUNK; k0 < sp * KCHUNK + KCHUNK; k0 += 64) {
    const unsigned short* kp = kb + (size_t)(k0 >> 4) * 1024;
    const unsigned short* vp = vb + (size_t)(k0 >> 5) * 2048;
    bf16x8 kf[8], vf[8];
#pragma unroll
    for (int i = 0; i < 8; ++i) kf[i] = ld8(kp + i * 512);
#pragma unroll
    for (int i = 0; i < 8; ++i) vf[i] = ld8(vp + i * 512);   // in flight early

    f32x4 sA0 = {0,0,0,0}, sA1 = {0,0,0,0}, sA2 = {0,0,0,0}, sA3 = {0,0,0,0};
    f32x4 sB0 = {0,0,0,0}, sB1 = {0,0,0,0}, sB2 = {0,0,0,0}, sB3 = {0,0,0,0};
    __builtin_amdgcn_s_setprio(1);
    sA0 = __builtin_amdgcn_mfma_f32_16x16x32_bf16(kf[0], qA0, sA0, 0,0,0);
    sA0 = __builtin_amdgcn_mfma_f32_16x16x32_bf16(kf[1], qA1, sA0, 0,0,0);
    sA1 = __builtin_amdgcn_mfma_f32_16x16x32_bf16(kf[2], qA0, sA1, 0,0,0);
    sA1 = __builtin_amdgcn_mfma_f32_16x16x32_bf16(kf[3], qA1, sA1, 0,0,0);
    sA2 = __builtin_amdgcn_mfma_f32_16x16x32_bf16(kf[4], qA0, sA2, 0,0,0);
    sA2 = __builtin_amdgcn_mfma_f32_16x16x32_bf16(kf[5], qA1, sA2, 0,0,0);
    sA3 = __builtin_amdgcn_mfma_f32_16x16x32_bf16(kf[6], qA0, sA3, 0,0,0);
    sA3 = __builtin_amdgcn_mfma_f32_16x16x32_bf16(kf[7], qA1, sA3, 0,0,0);
    sB0 = __builtin_amdgcn_mfma_f32_16x16x32_bf16(kf[0], qB0, sB0, 0,0,0);
    sB0 = __builtin_amdgcn_mfma_f32_16x16x32_bf16(kf[1], qB1, sB0, 0,0,0);
    sB1 = __builtin_amdgcn_mfma_f32_16x16x32_bf16(kf[2], qB0, sB1, 0,0,0);
    sB1 = __builtin_amdgcn_mfma_f32_16x16x32_bf16(kf[3], qB1, sB1, 0,0,0);
    sB2 = __builtin_amdgcn_mfma_f32_16x16x32_bf16(kf[4], qB0, sB2, 0,0,0);
    sB2 = __builtin_amdgcn_mfma_f32_16x16x32_bf16(kf[5], qB1, sB2, 0,0,0);
    sB3 = __builtin_amdgcn_mfma_f32_16x16x32_bf16(kf[6], qB0, sB3, 0,0,0);
    sB3 = __builtin_amdgcn_mfma_f32_16x16x32_bf16(kf[7], qB1, sB3, 0,0,0);
    __builtin_amdgcn_s_setprio(0);

    // ---- softmax tile A (overlaps sB MFMA latency) ----
    bf16x8 pfA0, pfA1, pfB0, pfB1;
    {
      float tmax = fmaxf(
          fmaxf(fmaxf(fmaxf(sA0[0], sA0[1]), fmaxf(sA0[2], sA0[3])),
                fmaxf(fmaxf(sA1[0], sA1[1]), fmaxf(sA1[2], sA1[3]))),
          fmaxf(fmaxf(fmaxf(sA2[0], sA2[1]), fmaxf(sA2[2], sA2[3])),
                fmaxf(fmaxf(sA3[0], sA3[1]), fmaxf(sA3[2], sA3[3]))));
      tmax = red16max(red32max(tmax));
      if (tmax > mA + 11.0f) {
        float fac = exp2_raw(mA - tmax);
        mA = tmax; lA *= fac;
        aA0 *= fac; aA1 *= fac; aA2 *= fac; aA3 *= fac;
      }
      float p[16];
#pragma unroll
      for (int r = 0; r < 4; ++r) {
        p[r]      = exp2_raw(sA0[r] - mA);
        p[4 + r]  = exp2_raw(sA1[r] - mA);
        p[8 + r]  = exp2_raw(sA2[r] - mA);
        p[12 + r] = exp2_raw(sA3[r] - mA);
      }
      lA += (((p[0]+p[1])+(p[2]+p[3])) + ((p[4]+p[5])+(p[6]+p[7]))) +
            (((p[8]+p[9])+(p[10]+p[11])) + ((p[12]+p[13])+(p[14]+p[15])));
      unsigned c0 = cvtpk(p[0], p[1]),   c1 = cvtpk(p[2], p[3]);
      unsigned c2 = cvtpk(p[4], p[5]),   c3 = cvtpk(p[6], p[7]);
      unsigned c4 = cvtpk(p[8], p[9]),   c5 = cvtpk(p[10], p[11]);
      unsigned c6 = cvtpk(p[12], p[13]), c7 = cvtpk(p[14], p[15]);
      pl32swap(c0, c2); pl32swap(c1, c3); pl16swap(c0, c2); pl16swap(c1, c3);
      pl32swap(c4, c6); pl32swap(c5, c7); pl16swap(c4, c6); pl16swap(c5, c7);
      u32x4 w0 = {c0, c1, c2, c3}, w1 = {c4, c5, c6, c7};
      pfA0 = __builtin_bit_cast(bf16x8, w0);
      pfA1 = __builtin_bit_cast(bf16x8, w1);
    }
    // ---- softmax tile B ----
    {
      float tmax = fmaxf(
          fmaxf(fmaxf(fmaxf(sB0[0], sB0[1]), fmaxf(sB0[2], sB0[3])),
                fmaxf(fmaxf(sB1[0], sB1[1]), fmaxf(sB1[2], sB1[3]))),
          fmaxf(fmaxf(fmaxf(sB2[0], sB2[1]), fmaxf(sB2[2], sB2[3])),
                fmaxf(fmaxf(sB3[0], sB3[1]), fmaxf(sB3[2], sB3[3]))));
      tmax = red16max(red32max(tmax));
      if (tmax > mB + 11.0f) {
        float fac = exp2_raw(mB - tmax);
        mB = tmax; lB *= fac;
        aB0 *= fac; aB1 *= fac; aB2 *= fac; aB3 *= fac;
      }
      float p[16];
#pragma unroll
      for (int r = 0; r < 4; ++r) {
        p[r]      = exp2_raw(sB0[r] - mB);
        p[4 + r]  = exp2_raw(sB1[r] - mB);
        p[8 + r]  = exp2_raw(sB2[r] - mB);
        p[12 + r] = exp2_raw(sB3[r] - mB);
      }
      lB += (((p[0]+p[1])+(p[2]+p[3])) + ((p[4]+p[5])+(p[6]+p[7]))) +
            (((p[8]+p[9])+(p[10]+p[11])) + ((p[12]+p[13])+(p[14]+p[15])));
      unsigned c0 = cvtpk(p[0], p[1]),   c1 = cvtpk(p[2], p[3]);
      unsigned c2 = cvtpk(p[4], p[5]),   c3 = cvtpk(p[6], p[7]);
      unsigned c4 = cvtpk(p[8], p[9]),   c5 = cvtpk(p[10], p[11]);
      unsigned c6 = cvtpk(p[12], p[13]), c7 = cvtpk(p[14], p[15]);
      pl32swap(c0, c2); pl32swap(c1, c3); pl16swap(c0, c2); pl16swap(c1, c3);
      pl32swap(c4, c6); pl32swap(c5, c7); pl16swap(c4, c6); pl16swap(c5, c7);
      u32x4 w0 = {c0, c1, c2, c3}, w1 = {c4, c5, c6, c7};
      pfB0 = __builtin_bit_cast(bf16x8, w0);
      pfB1 = __builtin_bit_cast(bf16x8, w1);
    }

    __builtin_amdgcn_s_setprio(1);
    aA0 = __builtin_amdgcn_mfma_f32_16x16x32_bf16(vf[0], pfA0, aA0, 0,0,0);
    aA1 = __builtin_amdgcn_mfma_f32_16x16x32_bf16(vf[1], pfA0, aA1, 0,0,0);
    aA2 = __builtin_amdgcn_mfma_f32_16x16x32_bf16(vf[2], pfA0, aA2, 0,0,0);
    aA3 = __builtin_amdgcn_mfma_f32_16x16x32_bf16(vf[3], pfA0, aA3, 0,0,0);
    aA0 = __builtin_amdgcn_mfma_f32_16x16x32_bf16(vf[4], pfA1, aA0, 0,0,0);
    aA1 = __builtin_amdgcn_mfma_f32_16x16x32_bf16(vf[5], pfA1, aA1, 0,0,0);
    aA2 = __builtin_amdgcn_mfma_f32_16x16x32_bf16(vf[6], pfA1, aA2, 0,0,0);
    aA3 = __builtin_amdgcn_mfma_f32_16x16x32_bf16(vf[7], pfA1, aA3, 0,0,0);
    aB0 = __builtin_amdgcn_mfma_f32_16x16x32_bf16(vf[0], pfB0, aB0, 0,0,0);
    aB1 = __builtin_amdgcn_mfma_f32_16x16x32_bf16(vf[1], pfB0, aB1, 0,0,0);
    aB2 = __builtin_amdgcn_mfma_f32_16x16x32_bf16(vf[2], pfB0, aB2, 0,0,0);
    aB3 = __builtin_amdgcn_mfma_f32_16x16x32_bf16(vf[3], pfB0, aB3, 0,0,0);
    aB0 = __builtin_amdgcn_mfma_f32_16x16x32_bf16(vf[4], pfB1, aB0, 0,0,0);
    aB1 = __builtin_amdgcn_mfma_f32_16x16x32_bf16(vf[5], pfB1, aB1, 0,0,0);
    aB2 = __builtin_amdgcn_mfma_f32_16x16x32_bf16(vf[6], pfB1, aB2, 0,0,0);
    aB3 = __builtin_amdgcn_mfma_f32_16x16x32_bf16(vf[7], pfB1, aB3, 0,0,0);
    __builtin_amdgcn_s_setprio(0);
  }

  const float lAr = red16sum(red32sum(lA));
  const float lBr = red16sum(red32sum(lB));

  // unnormalized bf16 partials + (m,l), per tile
  {
    unsigned short* pp = ctxp +
        (((size_t)(sp * BH + bh)) * SEQ + qt0 * 16 + lr) * DH + 4 * lg;
    short4v o0, o1, o2, o3;
#pragma unroll
    for (int r = 0; r < 4; ++r) {
      o0[r] = (short)f2bf(aA0[r]); o1[r] = (short)f2bf(aA1[r]);
      o2[r] = (short)f2bf(aA2[r]); o3[r] = (short)f2bf(aA3[r]);
    }
    *reinterpret_cast<short4v*>(pp)      = o0;
    *reinterpret_cast<short4v*>(pp + 16) = o1;
    *reinterpret_cast<short4v*>(pp + 32) = o2;
    *reinterpret_cast<short4v*>(pp + 48) = o3;
    if (lane < 16) {
      float2 v; v.x = mA; v.y = lAr;
      ml[(size_t)sp * (BH * SEQ) + bh * SEQ + qt0 * 16 + lr] = v;
    }
  }
  {
    unsigned short* pp = ctxp +
        (((size_t)(sp * BH + bh)) * SEQ + qt1 * 16 + lr) * DH + 4 * lg;
    short4v o0, o1, o2, o3;
#pragma unroll
    for (int r = 0; r < 4; ++r) {
      o0[r] = (short)f2bf(aB0[r]); o1[r] = (short)f2bf(aB1[r]);
      o2[r] = (short)f2bf(aB2[r]); o3[r] = (short)f2bf(aB3[r]);
    }
    *reinterpret_cast<short4v*>(pp)      = o0;
    *reinterpret_cast<short4v*>(pp + 16) = o1;
    *reinterpret_cast<short4v*>(pp + 32) = o2;
    *reinterpret_cast<short4v*>(pp + 48) = o3;
    if (lane < 16) {
      float2 v; v.x = mB; v.y = lBr;
      ml[(size_t)sp * (BH * SEQ) + bh * SEQ + qt1 * 16 + lr] = v;
    }
  }
}

// combine the NSPLIT partials -> ctx bf16 (B*S, 768)
__global__ __launch_bounds__(256) void attn_combine(
    const unsigned short* __restrict__ ctxp, const float2* __restrict__ ml,
    unsigned short* __restrict__ ctx) {
  const int idx = blockIdx.x * 256 + threadIdx.x;  // over BH*SEQ*DH
  const int d = idx & 63;
  const int row = idx >> 6;                        // bh*SEQ + s
  float m0 = ml[row].x,                 l0 = ml[row].y;
  float m1 = ml[row + BH*SEQ].x,        l1 = ml[row + BH*SEQ].y;
  float m2 = ml[row + 2*BH*SEQ].x,      l2 = ml[row + 2*BH*SEQ].y;
  float m3 = ml[row + 3*BH*SEQ].x,      l3 = ml[row + 3*BH*SEQ].y;
  float M = fmaxf(fmaxf(m0, m1), fmaxf(m2, m3));
  float w0 = exp2_raw(m0 - M), w1 = exp2_raw(m1 - M);
  float w2 = exp2_raw(m2 - M), w3 = exp2_raw(m3 - M);
  float den = w0 * l0 + w1 * l1 + w2 * l2 + w3 * l3;
  const size_t pstride = (size_t)BH * SEQ * DH;
  float num = w0 * bf2f(ctxp[(size_t)row * DH + d]) +
              w1 * bf2f(ctxp[(size_t)row * DH + d + pstride]) +
              w2 * bf2f(ctxp[(size_t)row * DH + d + 2 * pstride]) +
              w3 * bf2f(ctxp[(size_t)row * DH + d + 3 * pstride]);
  const int bh = row >> 11, s = row & (SEQ - 1);
  const int b = bh / HEADS, h = bh % HEADS;
  ctx[((size_t)(b * SEQ + s)) * CDIM + h * DH + d] = f2bf(num / den);
}

// ---------------------------------------------------------- add+rmsnorm ----
__global__ __launch_bounds__(256) void add_rmsnorm(
    const float* __restrict__ a, const float* __restrict__ b,
    float* __restrict__ outf, unsigned short* __restrict__ outb) {
  const int row = blockIdx.x;
  const int tid = threadIdx.x;
  const float* ap = a + (size_t)row * CDIM;
  const float* bp = b + (size_t)row * CDIM;
  float v0 = ap[tid]       + bp[tid];
  float v1 = ap[tid + 256] + bp[tid + 256];
  float v2 = ap[tid + 512] + bp[tid + 512];
  float ss = v0 * v0 + v1 * v1 + v2 * v2;
#pragma unroll
  for (int off = 32; off > 0; off >>= 1) ss += __shfl_xor(ss, off, 64);
  __shared__ float red[4];
  if ((tid & 63) == 0) red[tid >> 6] = ss;
  __syncthreads();
  float tot = red[0] + red[1] + red[2] + red[3];
  float r = rsqrtf(tot * (1.f / 768.f) + 1e-5f);
  float* of = outf + (size_t)row * CDIM;
  of[tid]       = v0 * r;
  of[tid + 256] = v1 * r;
  of[tid + 512] = v2 * r;
  if (outb) {
    unsigned short* ob = outb + (size_t)row * CDIM;
    ob[tid]       = f2bf(v0 * r);
    ob[tid + 256] = f2bf(v1 * r);
    ob[tid + 512] = f2bf(v2 * r);
  }
}

// ------------------------------------------------------------- silu*mul ----
__global__ __launch_bounds__(256) void silu_mul(
    const unsigned short* __restrict__ gu, unsigned short* __restrict__ hb) {
  const int i = blockIdx.x * 256 + threadIdx.x;  // < MROWS*INTER
  const int s = i >> 11, c = i & (INTER - 1);
  float g = bf2f(gu[(size_t)s * GU_N + c]);
  float u = bf2f(gu[(size_t)s * GU_N + INTER + c]);
  float sig = 1.f / (1.f + __expf(-g));
  hb[i] = f2bf(g * sig * u);
}

// ----------------------------------------------------------------- host ----
extern "C" void kernel_launch(void* const* d_in, const int* in_sizes, int n_in,
                              void* d_out, int out_size, void* d_ws, size_t ws_size,
                              hipStream_t stream) {
  const float* hidden = (const float*)d_in[0];
  const float* cosT   = (const float*)d_in[1];
  const float* sinT   = (const float*)d_in[2];
  const float* wqkv   = (const float*)d_in[3];
  const float* wo     = (const float*)d_in[4];
  const float* wgu    = (const float*)d_in[5];
  const float* wd     = (const float*)d_in[6];
  float* out = (float*)d_out;

  char* wsp = (char*)d_ws;
  size_t off = 0;
  auto alloc = [&](size_t bytes) { void* p = wsp + off; off += bytes; return p; };

  // persistent
  unsigned short* wqkvb = (unsigned short*)alloc(2ull * 1769472);
  unsigned short* wob   = (unsigned short*)alloc(2ull * 589824);
  unsigned short* wgub  = (unsigned short*)alloc(2ull * 3145728);
  unsigned short* wdb   = (unsigned short*)alloc(2ull * 1572864);
  unsigned short* hb    = (unsigned short*)alloc(2ull * 3145728);
  float*          x     = (float*)alloc(4ull * 3145728);
  unsigned short* xb    = (unsigned short*)alloc(2ull * 3145728);
  const size_t roff = off;

  // phase A (through attention)
  unsigned short* qkvb = (unsigned short*)alloc(2ull * MROWS * QKV_N);
  unsigned short* qT   = (unsigned short*)alloc(2ull * MROWS * CDIM);
  unsigned short* kT   = (unsigned short*)alloc(2ull * MROWS * CDIM);
  unsigned short* vTb  = (unsigned short*)alloc(2ull * MROWS * CDIM);
  unsigned short* ctx  = (unsigned short*)alloc(2ull * MROWS * CDIM);
  float*          attn = (float*)alloc(4ull * MROWS * CDIM);
  unsigned short* ctxp = (unsigned short*)alloc(2ull * NSPLIT * BH * SEQ * DH);
  float2*         ml   = (float2*)alloc(8ull * NSPLIT * BH * SEQ);

  // phase B (MLP) aliases phase A
  off = roff;
  unsigned short* gub  = (unsigned short*)alloc(2ull * MROWS * GU_N);
  unsigned short* hmid = (unsigned short*)alloc(2ull * MROWS * INTER);
  float*          mlp  = (float*)alloc(4ull * MROWS * CDIM);
  (void)ws_size; (void)in_sizes; (void)n_in; (void)out_size;

  // 1. casts
  cast_all<<<2048, 256, 0, stream>>>(hidden, wqkv, wo, wgu, wd,
                                     hb, wqkvb, wob, wgub, wdb);
  // 2. qkv = hidden @ w_qkv^T (bf16 out)
  gemm_lds<128, true><<<dim3(QKV_N / 128, MROWS / 128), 256, 0, stream>>>(
      hb, wqkvb, qkvb, MROWS, QKV_N, CDIM);
  // 3. rope (q,k) + v transpose into fragment-order tiles
  rope_qk<<<(MROWS * 24) / 4, 256, 0, stream>>>(qkvb, cosT, sinT, qT, kT);
  v_trans<<<dim3(BH, SEQ / 64), 256, 0, stream>>>(qkvb, vTb);
  // 4. attention (KV-split, 32 q-rows/wave) + combine
  attn_fused<<<(BH * (SEQ / 32) * NSPLIT) / 4, 256, 0, stream>>>(
      qT, kT, vTb, ctxp, ml);
  attn_combine<<<(BH * SEQ * DH) / 256, 256, 0, stream>>>(ctxp, ml, ctx);
  // 5. attn_out = ctx @ w_o^T  (BN=64 -> 384 blocks)
  gemm_lds<64, false><<<dim3(CDIM / 64, MROWS / 128), 256, 0, stream>>>(
      ctx, wob, attn, MROWS, CDIM, CDIM);
  // 6. x = rmsnorm(hidden + attn)
  add_rmsnorm<<<MROWS, 256, 0, stream>>>(hidden, attn, x, xb);
  // 7. gu = x @ w_gate_up^T (bf16 out)
  gemm_lds<128, true><<<dim3(GU_N / 128, MROWS / 128), 256, 0, stream>>>(
      xb, wgub, gub, MROWS, GU_N, CDIM);
  // 8. h = silu(gate)*up
  silu_mul<<<(MROWS * INTER) / 256, 256, 0, stream>>>(gub, hmid);
  // 9. mlp = h @ w_down^T  (BN=64 -> 384 blocks)
  gemm_lds<64, false><<<dim3(CDIM / 64, MROWS / 128), 256, 0, stream>>>(
      hmid, wdb, mlp, MROWS, CDIM, INTER);
  // 10. out = rmsnorm(x + mlp)
  add_rmsnorm<<<MROWS, 256, 0, stream>>>(x, mlp, out, nullptr);
}